// Round 10
// baseline (350.787 us; speedup 1.0000x reference)
//
#include <hip/hip_runtime.h>
#include <stdint.h>

#define IN_F  4096
#define OUT_F 4096

typedef __attribute__((ext_vector_type(8))) short bf16x8;
typedef __attribute__((ext_vector_type(4))) float f32x4;
typedef __attribute__((ext_vector_type(8))) unsigned short u16x8;

__device__ __forceinline__ unsigned short f2bf(float f) {
  union { float f; unsigned int u; } v; v.f = f;
  return (unsigned short)((v.u + 0x7FFFu + ((v.u >> 16) & 1u)) >> 16);
}

__device__ __forceinline__ void gload_lds16(void* lds, const void* g) {
  __builtin_amdgcn_global_load_lds((const __attribute__((address_space(1))) void*)g,
                                   (__attribute__((address_space(3))) void*)lds,
                                   16u, 0, 0u);
}

// ---------------- prep kernels ----------------

__global__ void cvt_x_kernel(const float* __restrict__ x,
                             unsigned short* __restrict__ o, long n8) {
  long i = (long)blockIdx.x * blockDim.x + threadIdx.x;
  long stride = (long)gridDim.x * blockDim.x;
  for (; i < n8; i += stride) {
    const float4* p = (const float4*)(x + i * 8);
    float4 a = p[0], b = p[1];
    u16x8 r;
    r[0] = f2bf(a.x); r[1] = f2bf(a.y); r[2] = f2bf(a.z); r[3] = f2bf(a.w);
    r[4] = f2bf(b.x); r[5] = f2bf(b.y); r[6] = f2bf(b.z); r[7] = f2bf(b.w);
    *(u16x8*)(o + i * 8) = r;
  }
}

// packed_weight arrives as int32 (harness widens uint8 -> int).
__global__ void dequant_w_kernel(const int* __restrict__ pw,
                                 const float* __restrict__ sp,
                                 const float* __restrict__ zpp,
                                 unsigned short* __restrict__ W) {
  const float scale = *sp, zp = *zpp;
  int i = blockIdx.x * blockDim.x + threadIdx.x;
  const int total = (OUT_F / 2) * (IN_F / 8);
  if (i >= total) return;
  int r = i / (IN_F / 8);
  int c = (i - r * (IN_F / 8)) * 8;
  const int* src = pw + (size_t)r * IN_F + c;
  int4 p0 = *(const int4*)(src);
  int4 p1 = *(const int4*)(src + 4);
  int bytes[8] = { p0.x, p0.y, p0.z, p0.w, p1.x, p1.y, p1.z, p1.w };
  u16x8 lo, hi;
#pragma unroll
  for (int j = 0; j < 8; ++j) {
    unsigned int b = (unsigned int)bytes[j] & 0xFFu;
    lo[j] = f2bf(scale * ((float)(b & 15u) - zp));
    hi[j] = f2bf(scale * ((float)(b >> 4) - zp));
  }
  *(u16x8*)(W + (size_t)(2 * r) * IN_F + c) = lo;
  *(u16x8*)(W + (size_t)(2 * r + 1) * IN_F + c) = hi;
}

// ====== 256x256 8-phase GEMM, m201 template with MINIMAL pinning ============
// Identical stage/read/VM schedule to r8 (hardware-verified correct), but:
//  - NO per-phase lgkmcnt(0): compiler emits counted lgkm waits per operand.
//  - NO sched_barrier(0) except immediately around each counted vmcnt
//    (prevents gload_lds / read motion across the VM accounting points --
//    the r3/r6 race mechanism). All other code motion is provably safe:
//    every read's guard VM is >=3 phases back except P4/P8 reads, which sit
//    directly under their own phase's SB0-pinned VM(4).
// Reads/phase: P1 A0(T) | P2 B1(T)->tau | P3 A1(T) | P4 B0(T+1)->tau
//            | P5 A0(T+1) | P6 B1(T+1)->sg | P7 A1(T+1) | P8 B0(T+2)->sg
// MFMA pairs:  P1(a,sg) P2(a,tau) P3(a,tau) P4(a,sg) P5(a,tau) P6(a,sg)
//              P7(a,sg) P8(a,tau)
// Stages [0,2,2,4,0,2,2,4]: P2 A(T+2)q0,q2 | P3 B(T+2)q0,q1
//   | P4 B(T+2)q2,q3 + A(T+2)q1,q3 | P6 A(T+3)q0,q2 | P7 B(T+3)q0,q1
//   | P8 B(T+3)q2,q3 + A(T+3)q1,q3.  VM(4) at P4/P8 start only.

#define BAR()   __builtin_amdgcn_s_barrier()
#define SB0()   __builtin_amdgcn_sched_barrier(0)
#define VM(n)   asm volatile("s_waitcnt vmcnt(" #n ")")

__global__ __launch_bounds__(512, 2)
void gemm256_kernel(const unsigned short* __restrict__ A,
                    const unsigned short* __restrict__ B,
                    const float* __restrict__ bias,
                    float* __restrict__ C, int M, int N, int K)
{
  __shared__ unsigned short sA[2 * 16384];   // [buf][256 rows][64] swizzled
  __shared__ unsigned short sB[2 * 16384];

  const int tid  = threadIdx.x;
  const int lane = tid & 63;
  const int wid  = tid >> 6;          // 0..7
  const int wm   = wid >> 2;          // 0..1
  const int wn   = wid & 3;           // 0..3

  // T1: XCD-aware bijective swizzle (grid = 512 = 8*64)
  const int cpx = gridDim.x >> 3;
  const int swz = ((int)blockIdx.x & 7) * cpx + ((int)blockIdx.x >> 3);
  const int ntn = N >> 8;
  const int tm = swz / ntn, tn = swz - tm * ntn;
  const int row0 = tm << 8, col0 = tn << 8;

  const int lrow = lane & 15;
  const int ko4  = lane >> 4;               // 0..3
  const int x7   = lrow & 7;
  const int cK0  = ((ko4 ^ x7) << 3);       // swizzled chunk offset, kk=0
  const int cK1  = (((4 + ko4) ^ x7) << 3); // kk=1

  // staging source pre-swizzle (involution with read-side XOR)
  const int srow   = tid >> 3;              // 0..63 within a 64-row quarter
  const int schunk = (tid & 7) ^ (srow & 7);

  f32x4 acc[8][4];
#pragma unroll
  for (int m = 0; m < 8; ++m)
#pragma unroll
    for (int n = 0; n < 4; ++n)
#pragma unroll
      for (int j = 0; j < 4; ++j) acc[m][n][j] = 0.0f;

  bf16x8 a[4][2];                 // single A slot [m2][kk]
  bf16x8 sg[2][2], tau[2][2];     // two B slots [n2][kk]

  // one 8 KiB quarter (64 rows x 64 cols) per gload
#define STAGE1(arr, buf, q, gbase, kt) \
    gload_lds16(arr + (buf)*16384 + (q)*4096 + wid*512, \
        (gbase) + (size_t)((q)*64 + srow) * K + (kt)*64 + schunk*8)

#define LDA_(buf, mh) do {                                                    \
    _Pragma("unroll")                                                         \
    for (int m2 = 0; m2 < 4; ++m2) {                                          \
      const int off_ = (buf)*16384 + (wm*128 + (mh)*64 + m2*16 + lrow)*64;    \
      a[m2][0] = *(const bf16x8*)(sA + off_ + cK0);                           \
      a[m2][1] = *(const bf16x8*)(sA + off_ + cK1);                           \
    } } while (0)

#define LDB_(dst, buf, nh) do {                                               \
    _Pragma("unroll")                                                         \
    for (int n2 = 0; n2 < 2; ++n2) {                                          \
      const int off_ = (buf)*16384 + (wn*64 + (nh)*32 + n2*16 + lrow)*64;     \
      dst[n2][0] = *(const bf16x8*)(sB + off_ + cK0);                         \
      dst[n2][1] = *(const bf16x8*)(sB + off_ + cK1);                         \
    } } while (0)

  // 16 MFMA, kk-outer (dependent acc pairs distance-8)
#define MFMA_MH(MH, bsrc, NH) do {                                            \
    __builtin_amdgcn_s_setprio(1);                                            \
    _Pragma("unroll")                                                         \
    for (int kk = 0; kk < 2; ++kk)                                            \
      _Pragma("unroll")                                                       \
      for (int m2 = 0; m2 < 4; ++m2)                                          \
        _Pragma("unroll")                                                     \
        for (int n2 = 0; n2 < 2; ++n2)                                        \
          acc[(MH)*4+m2][(NH)*2+n2] = __builtin_amdgcn_mfma_f32_16x16x32_bf16(\
              a[m2][kk], bsrc[n2][kk], acc[(MH)*4+m2][(NH)*2+n2], 0, 0, 0);   \
    __builtin_amdgcn_s_setprio(0);                                            \
  } while (0)

  const unsigned short* Ag = A + (size_t)row0 * K;
  const unsigned short* Bg = B + (size_t)col0 * K;

  // ---- prologue: tile0 (8) then tile1 (8); VM(8) -> tile0 landed ----
  STAGE1(sA, 0, 0, Ag, 0); STAGE1(sA, 0, 2, Ag, 0);
  STAGE1(sB, 0, 0, Bg, 0); STAGE1(sB, 0, 1, Bg, 0);
  STAGE1(sB, 0, 2, Bg, 0); STAGE1(sB, 0, 3, Bg, 0);
  STAGE1(sA, 0, 1, Ag, 0); STAGE1(sA, 0, 3, Ag, 0);
  STAGE1(sA, 1, 0, Ag, 1); STAGE1(sA, 1, 2, Ag, 1);
  STAGE1(sB, 1, 0, Bg, 1); STAGE1(sB, 1, 1, Bg, 1);
  STAGE1(sB, 1, 2, Bg, 1); STAGE1(sB, 1, 3, Bg, 1);
  STAGE1(sA, 1, 1, Ag, 1); STAGE1(sA, 1, 3, Ag, 1);
  SB0(); VM(8); SB0();
  BAR();
  LDB_(sg, 0, 0);           // B0(0) -> sg
  BAR();

  const int nkt = K >> 6;               // 64 K-tiles
  const int nit = nkt >> 1;             // 32 iterations
  for (int it = 0; it < nit; ++it) {
    const int T  = 2 * it;
    const int k2 = (T + 2 < nkt) ? T + 2 : nkt - 1;  // clamped stages land in
    const int k3 = (T + 3 < nkt) ? T + 3 : nkt - 1;  // regions w/ no live reader
    // P1: read A0(T); MFMA(a, sg=B0(T))
    LDA_(0, 0);
    BAR();
    MFMA_MH(0, sg, 0);
    BAR();
    // P2: read B1(T)->tau; stage A(T+2)q0,q2; MFMA(a, tau)
    LDB_(tau, 0, 1);
    STAGE1(sA, 0, 0, Ag, k2); STAGE1(sA, 0, 2, Ag, k2);
    BAR();
    MFMA_MH(0, tau, 1);
    BAR();
    // P3: read A1(T); stage B(T+2)q0,q1; MFMA(a, tau=B1(T))
    LDA_(0, 1);
    STAGE1(sB, 0, 0, Bg, k2); STAGE1(sB, 0, 1, Bg, k2);
    BAR();
    MFMA_MH(1, tau, 1);
    BAR();
    // P4: VM(4); read B0(T+1)->tau; stage B(T+2)q2,q3 + A(T+2)q1,q3;
    //     MFMA(a, sg=B0(T))
    SB0(); VM(4); SB0();
    LDB_(tau, 1, 0);
    STAGE1(sB, 0, 2, Bg, k2); STAGE1(sB, 0, 3, Bg, k2);
    STAGE1(sA, 0, 1, Ag, k2); STAGE1(sA, 0, 3, Ag, k2);
    BAR();
    MFMA_MH(1, sg, 0);
    BAR();
    // P5: read A0(T+1); MFMA(a, tau=B0(T+1))
    LDA_(1, 0);
    BAR();
    MFMA_MH(0, tau, 0);
    BAR();
    // P6: read B1(T+1)->sg; stage A(T+3)q0,q2; MFMA(a, sg)
    LDB_(sg, 1, 1);
    STAGE1(sA, 1, 0, Ag, k3); STAGE1(sA, 1, 2, Ag, k3);
    BAR();
    MFMA_MH(0, sg, 1);
    BAR();
    // P7: read A1(T+1); stage B(T+3)q0,q1; MFMA(a, sg=B1(T+1))
    LDA_(1, 1);
    STAGE1(sB, 1, 0, Bg, k3); STAGE1(sB, 1, 1, Bg, k3);
    BAR();
    MFMA_MH(1, sg, 1);
    BAR();
    // P8: VM(4); read B0(T+2)->sg; stage B(T+3)q2,q3 + A(T+3)q1,q3;
    //     MFMA(a, tau=B0(T+1))
    SB0(); VM(4); SB0();
    LDB_(sg, 0, 0);
    STAGE1(sB, 1, 2, Bg, k3); STAGE1(sB, 1, 3, Bg, k3);
    STAGE1(sA, 1, 1, Ag, k3); STAGE1(sA, 1, 3, Ag, k3);
    BAR();
    MFMA_MH(1, tau, 0);
    BAR();
  }

  asm volatile("s_waitcnt vmcnt(0)" ::: "memory");  // drain trailing stages

  // ---- epilogue ----
#pragma unroll
  for (int n = 0; n < 4; ++n) {
    const int col = col0 + wn * 64 + n * 16 + lrow;
    const float bv = bias[col];
#pragma unroll
    for (int m = 0; m < 8; ++m) {
      const int row = row0 + wm * 128 + m * 16 + ko4 * 4;
      const f32x4 v = acc[m][n];
#pragma unroll
      for (int j = 0; j < 4; ++j)
        C[(size_t)(row + j) * N + col] = v[j] + bv;
    }
  }
#undef STAGE1
#undef LDA_
#undef LDB_
#undef MFMA_MH
}

// ---------------- fallback 128x128 GEMM (correctness safety net) ----------

template <bool XB16>
__global__ __launch_bounds__(256)
void gemm_kernel(const unsigned short* __restrict__ Abf,
                 const float* __restrict__ Af32,
                 const unsigned short* __restrict__ Bbf,
                 const float* __restrict__ bias,
                 float* __restrict__ C, int M, int N, int K)
{
  __shared__ unsigned short sA[128 * 64];
  __shared__ unsigned short sB[128 * 64];
  const int tid  = threadIdx.x;
  const int lane = tid & 63;
  const int wid  = tid >> 6;
  const int wm = wid >> 1, wn = wid & 1;
  const int ntn = N / 128;
  const int tm = blockIdx.x / ntn, tn = blockIdx.x - tm * ntn;
  const int row0 = tm * 128, col0 = tn * 128;

  f32x4 acc[4][4];
#pragma unroll
  for (int m = 0; m < 4; ++m)
#pragma unroll
    for (int n = 0; n < 4; ++n)
#pragma unroll
      for (int j = 0; j < 4; ++j) acc[m][n][j] = 0.0f;

  const int lrow = lane & 15;
  const int lko  = (lane >> 4) * 8;

  for (int k0 = 0; k0 < K; k0 += 64) {
    if (XB16) {
#pragma unroll
      for (int i = 0; i < 4; ++i) {
        const int wbase = i * 256 + (wid << 6);
        const int c = wbase + lane;
        const int r = c >> 3, ce = (c & 7) * 8;
        gload_lds16(sA + (size_t)wbase * 8, Abf + (size_t)(row0 + r) * K + k0 + ce);
      }
    } else {
#pragma unroll
      for (int i = 0; i < 4; ++i) {
        const int c = i * 256 + tid;
        const int r = c >> 3, ce = (c & 7) * 8;
        const float4* p = (const float4*)(Af32 + (size_t)(row0 + r) * K + k0 + ce);
        float4 aa = p[0], bb = p[1];
        u16x8 v;
        v[0] = f2bf(aa.x); v[1] = f2bf(aa.y); v[2] = f2bf(aa.z); v[3] = f2bf(aa.w);
        v[4] = f2bf(bb.x); v[5] = f2bf(bb.y); v[6] = f2bf(bb.z); v[7] = f2bf(bb.w);
        *(u16x8*)(sA + c * 8) = v;
      }
    }
#pragma unroll
    for (int i = 0; i < 4; ++i) {
      const int wbase = i * 256 + (wid << 6);
      const int c = wbase + lane;
      const int r = c >> 3, ce = (c & 7) * 8;
      gload_lds16(sB + (size_t)wbase * 8, Bbf + (size_t)(col0 + r) * K + k0 + ce);
    }
    __syncthreads();
    bf16x8 af[4][2], bfr[4][2];
#pragma unroll
    for (int m = 0; m < 4; ++m) {
      const int r = wm * 64 + m * 16 + lrow;
#pragma unroll
      for (int kk = 0; kk < 2; ++kk)
        af[m][kk] = *(const bf16x8*)(sA + r * 64 + kk * 32 + lko);
    }
#pragma unroll
    for (int n = 0; n < 4; ++n) {
      const int r = wn * 64 + n * 16 + lrow;
#pragma unroll
      for (int kk = 0; kk < 2; ++kk)
        bfr[n][kk] = *(const bf16x8*)(sB + r * 64 + kk * 32 + lko);
    }
#pragma unroll
    for (int kk = 0; kk < 2; ++kk)
#pragma unroll
      for (int m = 0; m < 4; ++m)
#pragma unroll
        for (int n = 0; n < 4; ++n)
          acc[m][n] = __builtin_amdgcn_mfma_f32_16x16x32_bf16(
              af[m][kk], bfr[n][kk], acc[m][n], 0, 0, 0);
    __syncthreads();
  }
#pragma unroll
  for (int n = 0; n < 4; ++n) {
    const int col = col0 + wn * 64 + n * 16 + lrow;
    const float bv = bias[col];
#pragma unroll
    for (int m = 0; m < 4; ++m) {
      const int row = row0 + wm * 64 + m * 16 + (lane >> 4) * 4;
      const f32x4 v = acc[m][n];
#pragma unroll
      for (int j = 0; j < 4; ++j)
        C[(size_t)(row + j) * N + col] = v[j] + bv;
    }
  }
}

// ---------------- host launch ----------------

extern "C" void kernel_launch(void* const* d_in, const int* in_sizes, int n_in,
                              void* d_out, int out_size, void* d_ws, size_t ws_size,
                              hipStream_t stream) {
  const float* x      = (const float*)d_in[0];
  const int* pw       = (const int*)d_in[1];     // uint8 widened to int32
  const float* scale  = (const float*)d_in[2];
  const float* zp     = (const float*)d_in[3];
  const float* bias   = (const float*)d_in[4];
  float* out = (float*)d_out;

  const int K = IN_F, N = OUT_F;
  const int M = in_sizes[0] / K;                 // 8192

  const size_t xbytes = (size_t)M * K * 2;       // 64 MiB
  const size_t wbytes = (size_t)N * K * 2;       // 32 MiB

  if (ws_size >= xbytes + wbytes && (M & 255) == 0) {
    unsigned short* Xb = (unsigned short*)d_ws;
    unsigned short* Wb = (unsigned short*)((char*)d_ws + xbytes);
    cvt_x_kernel<<<2048, 256, 0, stream>>>(x, Xb, (long)M * K / 8);
    dequant_w_kernel<<<(OUT_F / 2) * (IN_F / 8) / 256, 256, 0, stream>>>(pw, scale, zp, Wb);
    gemm256_kernel<<<(M / 256) * (N / 256), 512, 0, stream>>>(Xb, Wb, bias, out, M, N, K);
  } else if (ws_size >= xbytes + wbytes) {
    unsigned short* Xb = (unsigned short*)d_ws;
    unsigned short* Wb = (unsigned short*)((char*)d_ws + xbytes);
    cvt_x_kernel<<<2048, 256, 0, stream>>>(x, Xb, (long)M * K / 8);
    dequant_w_kernel<<<(OUT_F / 2) * (IN_F / 8) / 256, 256, 0, stream>>>(pw, scale, zp, Wb);
    gemm_kernel<true><<<(M / 128) * (N / 128), 256, 0, stream>>>(
        Xb, nullptr, Wb, bias, out, M, N, K);
  } else {
    unsigned short* Wb = (unsigned short*)d_ws;  // requires >= 32 MiB ws
    dequant_w_kernel<<<(OUT_F / 2) * (IN_F / 8) / 256, 256, 0, stream>>>(pw, scale, zp, Wb);
    gemm_kernel<false><<<(M / 128) * (N / 128), 256, 0, stream>>>(
        nullptr, x, Wb, bias, out, M, N, K);
  }
}

// Round 11
// 334.103 us; speedup vs baseline: 1.0499x; 1.0499x over previous
//
#include <hip/hip_runtime.h>
#include <stdint.h>

#define IN_F  4096
#define OUT_F 4096

typedef __attribute__((ext_vector_type(8))) short bf16x8;
typedef __attribute__((ext_vector_type(4))) float f32x4;
typedef __attribute__((ext_vector_type(8))) unsigned short u16x8;

__device__ __forceinline__ unsigned short f2bf(float f) {
  union { float f; unsigned int u; } v; v.f = f;
  return (unsigned short)((v.u + 0x7FFFu + ((v.u >> 16) & 1u)) >> 16);
}

__device__ __forceinline__ void gload_lds16(void* lds, const void* g) {
  __builtin_amdgcn_global_load_lds((const __attribute__((address_space(1))) void*)g,
                                   (__attribute__((address_space(3))) void*)lds,
                                   16u, 0, 0u);
}

// ---------------- prep kernels ----------------

__global__ void cvt_x_kernel(const float* __restrict__ x,
                             unsigned short* __restrict__ o, long n8) {
  long i = (long)blockIdx.x * blockDim.x + threadIdx.x;
  long stride = (long)gridDim.x * blockDim.x;
  for (; i < n8; i += stride) {
    const float4* p = (const float4*)(x + i * 8);
    float4 a = p[0], b = p[1];
    u16x8 r;
    r[0] = f2bf(a.x); r[1] = f2bf(a.y); r[2] = f2bf(a.z); r[3] = f2bf(a.w);
    r[4] = f2bf(b.x); r[5] = f2bf(b.y); r[6] = f2bf(b.z); r[7] = f2bf(b.w);
    *(u16x8*)(o + i * 8) = r;
  }
}

// packed_weight arrives as int32 (harness widens uint8 -> int).
__global__ void dequant_w_kernel(const int* __restrict__ pw,
                                 const float* __restrict__ sp,
                                 const float* __restrict__ zpp,
                                 unsigned short* __restrict__ W) {
  const float scale = *sp, zp = *zpp;
  int i = blockIdx.x * blockDim.x + threadIdx.x;
  const int total = (OUT_F / 2) * (IN_F / 8);
  if (i >= total) return;
  int r = i / (IN_F / 8);
  int c = (i - r * (IN_F / 8)) * 8;
  const int* src = pw + (size_t)r * IN_F + c;
  int4 p0 = *(const int4*)(src);
  int4 p1 = *(const int4*)(src + 4);
  int bytes[8] = { p0.x, p0.y, p0.z, p0.w, p1.x, p1.y, p1.z, p1.w };
  u16x8 lo, hi;
#pragma unroll
  for (int j = 0; j < 8; ++j) {
    unsigned int b = (unsigned int)bytes[j] & 0xFFu;
    lo[j] = f2bf(scale * ((float)(b & 15u) - zp));
    hi[j] = f2bf(scale * ((float)(b >> 4) - zp));
  }
  *(u16x8*)(W + (size_t)(2 * r) * IN_F + c) = lo;
  *(u16x8*)(W + (size_t)(2 * r + 1) * IN_F + c) = hi;
}

// ====== 256x256 8-phase GEMM, SINGLE barrier per phase ======================
// Same stage/read/VM schedule as r8/r9 (hardware-verified correct twice).
// One s_barrier per phase at phase START; reads+stages, then MFMA at phase
// END, no mid-phase or trailing barrier. Safety:
//  - WAR (stage k over region read at j<k): read(j) is consumed by MFMA(j)
//    in the SAME phase (counted lgkm => serviced before MFMA issue), so every
//    wave's reads are serviced before it arrives at BAR(k); stage(k) issues
//    after BAR(k). Verified per-quarter for all 8 stage units (q0q2/q1q3 and
//    q0q1/q2q3 splits are disjoint from adjacent-phase reads).
//  - RAW (stage -> read): VM(4) FIFO accounting unchanged (wave-local,
//    barrier-independent); iter-0 + steady state re-enumerated. vmcnt must
//    stay 4 (6 would leave prev-P8's A q1,q3 undrained at P5's read).
// Reads/phase: P1 A0(T) | P2 B1(T)->tau | P3 A1(T) | P4 B0(T+1)->tau
//            | P5 A0(T+1) | P6 B1(T+1)->sg | P7 A1(T+1) | P8 B0(T+2)->sg
// MFMA:        P1(a,sg) P2(a,tau) P3(a,tau) P4(a,sg) P5(a,tau) P6(a,sg)
//              P7(a,sg) P8(a,tau)
// Stages [0,2,2,4,0,2,2,4]: P2 A(T+2)q0,q2 | P3 B(T+2)q0,q1
//   | P4 B(T+2)q2,q3 + A(T+2)q1,q3 | P6 A(T+3)q0,q2 | P7 B(T+3)q0,q1
//   | P8 B(T+3)q2,q3 + A(T+3)q1,q3.  VM(4) at P4/P8 (SB0-sandwiched).

#define BAR()   __builtin_amdgcn_s_barrier()
#define SB0()   __builtin_amdgcn_sched_barrier(0)
#define VM(n)   asm volatile("s_waitcnt vmcnt(" #n ")")

__global__ __launch_bounds__(512, 2)
void gemm256_kernel(const unsigned short* __restrict__ A,
                    const unsigned short* __restrict__ B,
                    const float* __restrict__ bias,
                    float* __restrict__ C, int M, int N, int K)
{
  __shared__ unsigned short sA[2 * 16384];   // [buf][256 rows][64] swizzled
  __shared__ unsigned short sB[2 * 16384];

  const int tid  = threadIdx.x;
  const int lane = tid & 63;
  const int wid  = tid >> 6;          // 0..7
  const int wm   = wid >> 2;          // 0..1
  const int wn   = wid & 3;           // 0..3

  // T1: XCD-aware bijective swizzle (grid = 512 = 8*64)
  const int cpx = gridDim.x >> 3;
  const int swz = ((int)blockIdx.x & 7) * cpx + ((int)blockIdx.x >> 3);
  const int ntn = N >> 8;
  const int tm = swz / ntn, tn = swz - tm * ntn;
  const int row0 = tm << 8, col0 = tn << 8;

  const int lrow = lane & 15;
  const int ko4  = lane >> 4;               // 0..3
  const int x7   = lrow & 7;
  const int cK0  = ((ko4 ^ x7) << 3);       // swizzled chunk offset, kk=0
  const int cK1  = (((4 + ko4) ^ x7) << 3); // kk=1

  // staging source pre-swizzle (involution with read-side XOR)
  const int srow   = tid >> 3;              // 0..63 within a 64-row quarter
  const int schunk = (tid & 7) ^ (srow & 7);

  f32x4 acc[8][4];
#pragma unroll
  for (int m = 0; m < 8; ++m)
#pragma unroll
    for (int n = 0; n < 4; ++n)
#pragma unroll
      for (int j = 0; j < 4; ++j) acc[m][n][j] = 0.0f;

  bf16x8 a[4][2];                 // single A slot [m2][kk]
  bf16x8 sg[2][2], tau[2][2];     // two B slots [n2][kk]

  // one 8 KiB quarter (64 rows x 64 cols) per gload
#define STAGE1(arr, buf, q, gbase, kt) \
    gload_lds16(arr + (buf)*16384 + (q)*4096 + wid*512, \
        (gbase) + (size_t)((q)*64 + srow) * K + (kt)*64 + schunk*8)

#define LDA_(buf, mh) do {                                                    \
    _Pragma("unroll")                                                         \
    for (int m2 = 0; m2 < 4; ++m2) {                                          \
      const int off_ = (buf)*16384 + (wm*128 + (mh)*64 + m2*16 + lrow)*64;    \
      a[m2][0] = *(const bf16x8*)(sA + off_ + cK0);                           \
      a[m2][1] = *(const bf16x8*)(sA + off_ + cK1);                           \
    } } while (0)

#define LDB_(dst, buf, nh) do {                                               \
    _Pragma("unroll")                                                         \
    for (int n2 = 0; n2 < 2; ++n2) {                                          \
      const int off_ = (buf)*16384 + (wn*64 + (nh)*32 + n2*16 + lrow)*64;     \
      dst[n2][0] = *(const bf16x8*)(sB + off_ + cK0);                         \
      dst[n2][1] = *(const bf16x8*)(sB + off_ + cK1);                         \
    } } while (0)

  // 16 MFMA, kk-outer (dependent acc pairs distance-8)
#define MFMA_MH(MH, bsrc, NH) do {                                            \
    __builtin_amdgcn_s_setprio(1);                                            \
    _Pragma("unroll")                                                         \
    for (int kk = 0; kk < 2; ++kk)                                            \
      _Pragma("unroll")                                                       \
      for (int m2 = 0; m2 < 4; ++m2)                                          \
        _Pragma("unroll")                                                     \
        for (int n2 = 0; n2 < 2; ++n2)                                        \
          acc[(MH)*4+m2][(NH)*2+n2] = __builtin_amdgcn_mfma_f32_16x16x32_bf16(\
              a[m2][kk], bsrc[n2][kk], acc[(MH)*4+m2][(NH)*2+n2], 0, 0, 0);   \
    __builtin_amdgcn_s_setprio(0);                                            \
  } while (0)

  const unsigned short* Ag = A + (size_t)row0 * K;
  const unsigned short* Bg = B + (size_t)col0 * K;

  // ---- prologue: tile0 (8) then tile1 (8); VM(8) -> tile0 landed ----
  STAGE1(sA, 0, 0, Ag, 0); STAGE1(sA, 0, 2, Ag, 0);
  STAGE1(sB, 0, 0, Bg, 0); STAGE1(sB, 0, 1, Bg, 0);
  STAGE1(sB, 0, 2, Bg, 0); STAGE1(sB, 0, 3, Bg, 0);
  STAGE1(sA, 0, 1, Ag, 0); STAGE1(sA, 0, 3, Ag, 0);
  STAGE1(sA, 1, 0, Ag, 1); STAGE1(sA, 1, 2, Ag, 1);
  STAGE1(sB, 1, 0, Bg, 1); STAGE1(sB, 1, 1, Bg, 1);
  STAGE1(sB, 1, 2, Bg, 1); STAGE1(sB, 1, 3, Bg, 1);
  STAGE1(sA, 1, 1, Ag, 1); STAGE1(sA, 1, 3, Ag, 1);
  SB0(); VM(8); SB0();
  BAR();
  LDB_(sg, 0, 0);           // B0(0) -> sg  (buf0 fully drained by VM(8))

  const int nkt = K >> 6;               // 64 K-tiles
  const int nit = nkt >> 1;             // 32 iterations
  for (int it = 0; it < nit; ++it) {
    const int T  = 2 * it;
    const int k2 = (T + 2 < nkt) ? T + 2 : nkt - 1;  // clamped stages land in
    const int k3 = (T + 3 < nkt) ? T + 3 : nkt - 1;  // regions w/ no live reader
    // P1: read A0(T); MFMA(a, sg=B0(T))
    BAR(); SB0();
    LDA_(0, 0);
    MFMA_MH(0, sg, 0);
    // P2: read B1(T)->tau; stage A(T+2)q0,q2; MFMA(a, tau)
    BAR(); SB0();
    LDB_(tau, 0, 1);
    STAGE1(sA, 0, 0, Ag, k2); STAGE1(sA, 0, 2, Ag, k2);
    MFMA_MH(0, tau, 1);
    // P3: read A1(T); stage B(T+2)q0,q1; MFMA(a, tau=B1(T))
    BAR(); SB0();
    LDA_(0, 1);
    STAGE1(sB, 0, 0, Bg, k2); STAGE1(sB, 0, 1, Bg, k2);
    MFMA_MH(1, tau, 1);
    // P4: VM(4); read B0(T+1)->tau; stage B(T+2)q2,q3 + A(T+2)q1,q3;
    //     MFMA(a, sg=B0(T))
    BAR(); SB0(); VM(4); SB0();
    LDB_(tau, 1, 0);
    STAGE1(sB, 0, 2, Bg, k2); STAGE1(sB, 0, 3, Bg, k2);
    STAGE1(sA, 0, 1, Ag, k2); STAGE1(sA, 0, 3, Ag, k2);
    MFMA_MH(1, sg, 0);
    // P5: read A0(T+1); MFMA(a, tau=B0(T+1))
    BAR(); SB0();
    LDA_(1, 0);
    MFMA_MH(0, tau, 0);
    // P6: read B1(T+1)->sg; stage A(T+3)q0,q2; MFMA(a, sg)
    BAR(); SB0();
    LDB_(sg, 1, 1);
    STAGE1(sA, 1, 0, Ag, k3); STAGE1(sA, 1, 2, Ag, k3);
    MFMA_MH(0, sg, 1);
    // P7: read A1(T+1); stage B(T+3)q0,q1; MFMA(a, sg=B1(T+1))
    BAR(); SB0();
    LDA_(1, 1);
    STAGE1(sB, 1, 0, Bg, k3); STAGE1(sB, 1, 1, Bg, k3);
    MFMA_MH(1, sg, 1);
    // P8: VM(4); read B0(T+2)->sg; stage B(T+3)q2,q3 + A(T+3)q1,q3;
    //     MFMA(a, tau=B0(T+1))
    BAR(); SB0(); VM(4); SB0();
    LDB_(sg, 0, 0);
    STAGE1(sB, 1, 2, Bg, k3); STAGE1(sB, 1, 3, Bg, k3);
    STAGE1(sA, 1, 1, Ag, k3); STAGE1(sA, 1, 3, Ag, k3);
    MFMA_MH(1, tau, 0);
  }

  asm volatile("s_waitcnt vmcnt(0)" ::: "memory");  // drain trailing stages

  // ---- epilogue ----
#pragma unroll
  for (int n = 0; n < 4; ++n) {
    const int col = col0 + wn * 64 + n * 16 + lrow;
    const float bv = bias[col];
#pragma unroll
    for (int m = 0; m < 8; ++m) {
      const int row = row0 + wm * 128 + m * 16 + ko4 * 4;
      const f32x4 v = acc[m][n];
#pragma unroll
      for (int j = 0; j < 4; ++j)
        C[(size_t)(row + j) * N + col] = v[j] + bv;
    }
  }
#undef STAGE1
#undef LDA_
#undef LDB_
#undef MFMA_MH
}

// ---------------- fallback 128x128 GEMM (correctness safety net) ----------

template <bool XB16>
__global__ __launch_bounds__(256)
void gemm_kernel(const unsigned short* __restrict__ Abf,
                 const float* __restrict__ Af32,
                 const unsigned short* __restrict__ Bbf,
                 const float* __restrict__ bias,
                 float* __restrict__ C, int M, int N, int K)
{
  __shared__ unsigned short sA[128 * 64];
  __shared__ unsigned short sB[128 * 64];
  const int tid  = threadIdx.x;
  const int lane = tid & 63;
  const int wid  = tid >> 6;
  const int wm = wid >> 1, wn = wid & 1;
  const int ntn = N / 128;
  const int tm = blockIdx.x / ntn, tn = blockIdx.x - tm * ntn;
  const int row0 = tm * 128, col0 = tn * 128;

  f32x4 acc[4][4];
#pragma unroll
  for (int m = 0; m < 4; ++m)
#pragma unroll
    for (int n = 0; n < 4; ++n)
#pragma unroll
      for (int j = 0; j < 4; ++j) acc[m][n][j] = 0.0f;

  const int lrow = lane & 15;
  const int lko  = (lane >> 4) * 8;

  for (int k0 = 0; k0 < K; k0 += 64) {
    if (XB16) {
#pragma unroll
      for (int i = 0; i < 4; ++i) {
        const int wbase = i * 256 + (wid << 6);
        const int c = wbase + lane;
        const int r = c >> 3, ce = (c & 7) * 8;
        gload_lds16(sA + (size_t)wbase * 8, Abf + (size_t)(row0 + r) * K + k0 + ce);
      }
    } else {
#pragma unroll
      for (int i = 0; i < 4; ++i) {
        const int c = i * 256 + tid;
        const int r = c >> 3, ce = (c & 7) * 8;
        const float4* p = (const float4*)(Af32 + (size_t)(row0 + r) * K + k0 + ce);
        float4 aa = p[0], bb = p[1];
        u16x8 v;
        v[0] = f2bf(aa.x); v[1] = f2bf(aa.y); v[2] = f2bf(aa.z); v[3] = f2bf(aa.w);
        v[4] = f2bf(bb.x); v[5] = f2bf(bb.y); v[6] = f2bf(bb.z); v[7] = f2bf(bb.w);
        *(u16x8*)(sA + c * 8) = v;
      }
    }
#pragma unroll
    for (int i = 0; i < 4; ++i) {
      const int wbase = i * 256 + (wid << 6);
      const int c = wbase + lane;
      const int r = c >> 3, ce = (c & 7) * 8;
      gload_lds16(sB + (size_t)wbase * 8, Bbf + (size_t)(col0 + r) * K + k0 + ce);
    }
    __syncthreads();
    bf16x8 af[4][2], bfr[4][2];
#pragma unroll
    for (int m = 0; m < 4; ++m) {
      const int r = wm * 64 + m * 16 + lrow;
#pragma unroll
      for (int kk = 0; kk < 2; ++kk)
        af[m][kk] = *(const bf16x8*)(sA + r * 64 + kk * 32 + lko);
    }
#pragma unroll
    for (int n = 0; n < 4; ++n) {
      const int r = wn * 64 + n * 16 + lrow;
#pragma unroll
      for (int kk = 0; kk < 2; ++kk)
        bfr[n][kk] = *(const bf16x8*)(sB + r * 64 + kk * 32 + lko);
    }
#pragma unroll
    for (int kk = 0; kk < 2; ++kk)
#pragma unroll
      for (int m = 0; m < 4; ++m)
#pragma unroll
        for (int n = 0; n < 4; ++n)
          acc[m][n] = __builtin_amdgcn_mfma_f32_16x16x32_bf16(
              af[m][kk], bfr[n][kk], acc[m][n], 0, 0, 0);
    __syncthreads();
  }
#pragma unroll
  for (int n = 0; n < 4; ++n) {
    const int col = col0 + wn * 64 + n * 16 + lrow;
    const float bv = bias[col];
#pragma unroll
    for (int m = 0; m < 4; ++m) {
      const int row = row0 + wm * 64 + m * 16 + (lane >> 4) * 4;
      const f32x4 v = acc[m][n];
#pragma unroll
      for (int j = 0; j < 4; ++j)
        C[(size_t)(row + j) * N + col] = v[j] + bv;
    }
  }
}

// ---------------- host launch ----------------

extern "C" void kernel_launch(void* const* d_in, const int* in_sizes, int n_in,
                              void* d_out, int out_size, void* d_ws, size_t ws_size,
                              hipStream_t stream) {
  const float* x      = (const float*)d_in[0];
  const int* pw       = (const int*)d_in[1];     // uint8 widened to int32
  const float* scale  = (const float*)d_in[2];
  const float* zp     = (const float*)d_in[3];
  const float* bias   = (const float*)d_in[4];
  float* out = (float*)d_out;

  const int K = IN_F, N = OUT_F;
  const int M = in_sizes[0] / K;                 // 8192

  const size_t xbytes = (size_t)M * K * 2;       // 64 MiB
  const size_t wbytes = (size_t)N * K * 2;       // 32 MiB

  if (ws_size >= xbytes + wbytes && (M & 255) == 0) {
    unsigned short* Xb = (unsigned short*)d_ws;
    unsigned short* Wb = (unsigned short*)((char*)d_ws + xbytes);
    cvt_x_kernel<<<2048, 256, 0, stream>>>(x, Xb, (long)M * K / 8);
    dequant_w_kernel<<<(OUT_F / 2) * (IN_F / 8) / 256, 256, 0, stream>>>(pw, scale, zp, Wb);
    gemm256_kernel<<<(M / 256) * (N / 256), 512, 0, stream>>>(Xb, Wb, bias, out, M, N, K);
  } else if (ws_size >= xbytes + wbytes) {
    unsigned short* Xb = (unsigned short*)d_ws;
    unsigned short* Wb = (unsigned short*)((char*)d_ws + xbytes);
    cvt_x_kernel<<<2048, 256, 0, stream>>>(x, Xb, (long)M * K / 8);
    dequant_w_kernel<<<(OUT_F / 2) * (IN_F / 8) / 256, 256, 0, stream>>>(pw, scale, zp, Wb);
    gemm_kernel<true><<<(M / 128) * (N / 128), 256, 0, stream>>>(
        Xb, nullptr, Wb, bias, out, M, N, K);
  } else {
    unsigned short* Wb = (unsigned short*)d_ws;  // requires >= 32 MiB ws
    dequant_w_kernel<<<(OUT_F / 2) * (IN_F / 8) / 256, 256, 0, stream>>>(pw, scale, zp, Wb);
    gemm_kernel<false><<<(M / 128) * (N / 128), 256, 0, stream>>>(
        nullptr, x, Wb, bias, out, M, N, K);
  }
}

// Round 12
// 301.248 us; speedup vs baseline: 1.1644x; 1.1091x over previous
//
#include <hip/hip_runtime.h>
#include <stdint.h>

#define IN_F  4096
#define OUT_F 4096

typedef __attribute__((ext_vector_type(8))) short bf16x8;
typedef __attribute__((ext_vector_type(4))) float f32x4;
typedef __attribute__((ext_vector_type(16))) float f32x16;
typedef __attribute__((ext_vector_type(8))) unsigned short u16x8;

__device__ __forceinline__ unsigned short f2bf(float f) {
  union { float f; unsigned int u; } v; v.f = f;
  return (unsigned short)((v.u + 0x7FFFu + ((v.u >> 16) & 1u)) >> 16);
}

__device__ __forceinline__ void gload_lds16(void* lds, const void* g) {
  __builtin_amdgcn_global_load_lds((const __attribute__((address_space(1))) void*)g,
                                   (__attribute__((address_space(3))) void*)lds,
                                   16u, 0, 0u);
}

// ---------------- prep kernels ----------------

__global__ void cvt_x_kernel(const float* __restrict__ x,
                             unsigned short* __restrict__ o, long n8) {
  long i = (long)blockIdx.x * blockDim.x + threadIdx.x;
  long stride = (long)gridDim.x * blockDim.x;
  for (; i < n8; i += stride) {
    const float4* p = (const float4*)(x + i * 8);
    float4 a = p[0], b = p[1];
    u16x8 r;
    r[0] = f2bf(a.x); r[1] = f2bf(a.y); r[2] = f2bf(a.z); r[3] = f2bf(a.w);
    r[4] = f2bf(b.x); r[5] = f2bf(b.y); r[6] = f2bf(b.z); r[7] = f2bf(b.w);
    *(u16x8*)(o + i * 8) = r;
  }
}

// packed_weight arrives as int32 (harness widens uint8 -> int).
__global__ void dequant_w_kernel(const int* __restrict__ pw,
                                 const float* __restrict__ sp,
                                 const float* __restrict__ zpp,
                                 unsigned short* __restrict__ W) {
  const float scale = *sp, zp = *zpp;
  int i = blockIdx.x * blockDim.x + threadIdx.x;
  const int total = (OUT_F / 2) * (IN_F / 8);
  if (i >= total) return;
  int r = i / (IN_F / 8);
  int c = (i - r * (IN_F / 8)) * 8;
  const int* src = pw + (size_t)r * IN_F + c;
  int4 p0 = *(const int4*)(src);
  int4 p1 = *(const int4*)(src + 4);
  int bytes[8] = { p0.x, p0.y, p0.z, p0.w, p1.x, p1.y, p1.z, p1.w };
  u16x8 lo, hi;
#pragma unroll
  for (int j = 0; j < 8; ++j) {
    unsigned int b = (unsigned int)bytes[j] & 0xFFu;
    lo[j] = f2bf(scale * ((float)(b & 15u) - zp));
    hi[j] = f2bf(scale * ((float)(b >> 4) - zp));
  }
  *(u16x8*)(W + (size_t)(2 * r) * IN_F + c) = lo;
  *(u16x8*)(W + (size_t)(2 * r + 1) * IN_F + c) = hi;
}

// ====== 256x256 8-phase GEMM on 32x32x16 MFMA (2495 vs 2176 TF pipe) =======
// Schedule/stages/VM identical to r11 (verified). NEW: group-transposed XOR
// LDS layout so 32-row fragment reads are conflict-free:
//   unit(row, ch) = row*8 + (ch ^ (row&7) ^ ((row>>3)&7))   [16B units,
//   per 8KiB quarter of 64 rows x 8 chunks]
// Read A-frag (32 rows): lane l -> bank-quad = hi ^ (l&7) ^ ((l>>3)&3) --
// each 8-lane sweep covers all 8 quads exactly once (enumerated). Stage side
// stays a LINEAR gload dest; source pre-swizzled per-lane (rule #21).
// Fragments: A row=lane&31, k=(lane>>5)*8..+7 (analogous to verified 16x16);
// C/D: col=lane&31, row=(reg&3)+8*(reg>>2)+4*(lane>>5) [m74/m101].
// Per phase: A-phase 8 ds_read_b128, B-phase 4; 8 MFMA 32x32x16 (ks-outer,
// dependent-acc distance 2); stages [0,2,2,4,0,2,2,4]; VM(4)@P4/P8.

#define BAR()   __builtin_amdgcn_s_barrier()
#define SB0()   __builtin_amdgcn_sched_barrier(0)
#define VM(n)   asm volatile("s_waitcnt vmcnt(" #n ")")

__global__ __launch_bounds__(512, 2)
void gemm256_kernel(const unsigned short* __restrict__ A,
                    const unsigned short* __restrict__ B,
                    const float* __restrict__ bias,
                    float* __restrict__ C, int M, int N, int K)
{
  __shared__ unsigned short sA[2 * 16384];   // [buf][4 quarters][64r x 8ch] gt-swz
  __shared__ unsigned short sB[2 * 16384];

  const int tid  = threadIdx.x;
  const int lane = tid & 63;
  const int wid  = tid >> 6;          // 0..7
  const int wm   = wid >> 2;          // 0..1
  const int wn   = wid & 3;           // 0..3

  // T1: XCD-aware bijective swizzle (grid = 512 = 8*64)
  const int cpx = gridDim.x >> 3;
  const int swz = ((int)blockIdx.x & 7) * cpx + ((int)blockIdx.x >> 3);
  const int ntn = N >> 8;
  const int tm = swz / ntn, tn = swz - tm * ntn;
  const int row0 = tm << 8, col0 = tn << 8;

  const int l31  = lane & 31;
  const int hi   = lane >> 5;                    // 0..1 k-half
  const int X0   = (lane & 7) ^ ((lane >> 3) & 3);
  const int aRow = l31 << 6;                     // (lane&31)*64 elements

  // staging: linear dest unit t=tid; holds row t>>3, stored-chunk t&7 ->
  // logical chunk = sc ^ (row&7) ^ ((row>>3)&7)
  const int srow   = tid >> 3;                   // 0..63 within quarter
  const int schunk = (tid & 7) ^ (srow & 7) ^ ((srow >> 3) & 7);

  f32x16 acc[4][2];
#pragma unroll
  for (int m = 0; m < 4; ++m)
#pragma unroll
    for (int n = 0; n < 2; ++n)
#pragma unroll
      for (int j = 0; j < 16; ++j) acc[m][n][j] = 0.0f;

  bf16x8 a[2][4];                 // A slot [fr][ks]
  bf16x8 sg[4], tau[4];           // two B slots [ks]

  // one 8 KiB quarter (64 rows x 64 K-elems) per gload
#define STAGE1(arr, buf, q, gbase, kt) \
    gload_lds16(arr + (buf)*16384 + (q)*4096 + wid*512, \
        (gbase) + (size_t)((q)*64 + srow) * K + (kt)*64 + schunk*8)

#define LDA_(buf, mh) do {                                                    \
    _Pragma("unroll")                                                         \
    for (int fr = 0; fr < 2; ++fr)                                            \
      _Pragma("unroll")                                                       \
      for (int ks = 0; ks < 4; ++ks) {                                        \
        const int off_ = (buf)*16384 + (wm*2 + (mh))*4096 + fr*2048 + aRow    \
            + ((((ks*2 + hi) ^ X0 ^ (fr << 2)) & 7) << 3);                    \
        a[fr][ks] = *(const bf16x8*)(sA + off_);                              \
      } } while (0)

#define LDB_(dst, buf, nh) do {                                               \
    _Pragma("unroll")                                                         \
    for (int ks = 0; ks < 4; ++ks) {                                          \
      const int off_ = (buf)*16384 + wn*4096 + (nh)*2048 + aRow               \
          + ((((ks*2 + hi) ^ X0 ^ ((nh) << 2)) & 7) << 3);                    \
      dst[ks] = *(const bf16x8*)(sB + off_);                                  \
    } } while (0)

  // 8 MFMA 32x32x16, ks-outer (dependent acc pairs distance-2)
#define MFMA_MH(MH, bsrc, NH) do {                                            \
    __builtin_amdgcn_s_setprio(1);                                            \
    _Pragma("unroll")                                                         \
    for (int ks = 0; ks < 4; ++ks)                                            \
      _Pragma("unroll")                                                       \
      for (int fr = 0; fr < 2; ++fr)                                          \
        acc[(MH)*2+fr][NH] = __builtin_amdgcn_mfma_f32_32x32x16_bf16(         \
            a[fr][ks], bsrc[ks], acc[(MH)*2+fr][NH], 0, 0, 0);                \
    __builtin_amdgcn_s_setprio(0);                                            \
  } while (0)

  const unsigned short* Ag = A + (size_t)row0 * K;
  const unsigned short* Bg = B + (size_t)col0 * K;

  // ---- prologue: tile0 (8) then tile1 (8); VM(8) -> tile0 landed ----
  STAGE1(sA, 0, 0, Ag, 0); STAGE1(sA, 0, 2, Ag, 0);
  STAGE1(sB, 0, 0, Bg, 0); STAGE1(sB, 0, 1, Bg, 0);
  STAGE1(sB, 0, 2, Bg, 0); STAGE1(sB, 0, 3, Bg, 0);
  STAGE1(sA, 0, 1, Ag, 0); STAGE1(sA, 0, 3, Ag, 0);
  STAGE1(sA, 1, 0, Ag, 1); STAGE1(sA, 1, 2, Ag, 1);
  STAGE1(sB, 1, 0, Bg, 1); STAGE1(sB, 1, 1, Bg, 1);
  STAGE1(sB, 1, 2, Bg, 1); STAGE1(sB, 1, 3, Bg, 1);
  STAGE1(sA, 1, 1, Ag, 1); STAGE1(sA, 1, 3, Ag, 1);
  SB0(); VM(8); SB0();
  BAR();
  LDB_(sg, 0, 0);           // B0(0) -> sg  (buf0 fully drained by VM(8))

  const int nkt = K >> 6;               // 64 K-tiles
  const int nit = nkt >> 1;             // 32 iterations
  for (int it = 0; it < nit; ++it) {
    const int T  = 2 * it;
    const int k2 = (T + 2 < nkt) ? T + 2 : nkt - 1;  // clamped stages land in
    const int k3 = (T + 3 < nkt) ? T + 3 : nkt - 1;  // regions w/ no live reader
    // P1: read A0(T); MFMA(a, sg=B0(T)) quadrant (0,0)
    BAR(); SB0();
    LDA_(0, 0);
    MFMA_MH(0, sg, 0);
    // P2: read B1(T)->tau; stage A(T+2)q0,q2; MFMA(a, tau) (0,1)
    BAR(); SB0();
    LDB_(tau, 0, 1);
    STAGE1(sA, 0, 0, Ag, k2); STAGE1(sA, 0, 2, Ag, k2);
    MFMA_MH(0, tau, 1);
    // P3: read A1(T); stage B(T+2)q0,q1; MFMA(a, tau=B1(T)) (1,1)
    BAR(); SB0();
    LDA_(0, 1);
    STAGE1(sB, 0, 0, Bg, k2); STAGE1(sB, 0, 1, Bg, k2);
    MFMA_MH(1, tau, 1);
    // P4: VM(4); read B0(T+1)->tau; stage B(T+2)q2,q3 + A(T+2)q1,q3;
    //     MFMA(a, sg=B0(T)) (1,0)
    BAR(); SB0(); VM(4); SB0();
    LDB_(tau, 1, 0);
    STAGE1(sB, 0, 2, Bg, k2); STAGE1(sB, 0, 3, Bg, k2);
    STAGE1(sA, 0, 1, Ag, k2); STAGE1(sA, 0, 3, Ag, k2);
    MFMA_MH(1, sg, 0);
    // P5: read A0(T+1); MFMA(a, tau=B0(T+1)) (0,0)
    BAR(); SB0();
    LDA_(1, 0);
    MFMA_MH(0, tau, 0);
    // P6: read B1(T+1)->sg; stage A(T+3)q0,q2; MFMA(a, sg) (0,1)
    BAR(); SB0();
    LDB_(sg, 1, 1);
    STAGE1(sA, 1, 0, Ag, k3); STAGE1(sA, 1, 2, Ag, k3);
    MFMA_MH(0, sg, 1);
    // P7: read A1(T+1); stage B(T+3)q0,q1; MFMA(a, sg=B1(T+1)) (1,1)
    BAR(); SB0();
    LDA_(1, 1);
    STAGE1(sB, 1, 0, Bg, k3); STAGE1(sB, 1, 1, Bg, k3);
    MFMA_MH(1, sg, 1);
    // P8: VM(4); read B0(T+2)->sg; stage B(T+3)q2,q3 + A(T+3)q1,q3;
    //     MFMA(a, tau=B0(T+1)) (1,0)
    BAR(); SB0(); VM(4); SB0();
    LDB_(sg, 0, 0);
    STAGE1(sB, 1, 2, Bg, k3); STAGE1(sB, 1, 3, Bg, k3);
    STAGE1(sA, 1, 1, Ag, k3); STAGE1(sA, 1, 3, Ag, k3);
    MFMA_MH(1, tau, 0);
  }

  asm volatile("s_waitcnt vmcnt(0)" ::: "memory");  // drain trailing stages

  // ---- epilogue: 32x32 C/D mapping (col=lane&31, row=(r&3)+8*(r>>2)+4*hi) --
#pragma unroll
  for (int gm = 0; gm < 4; ++gm) {
#pragma unroll
    for (int fc = 0; fc < 2; ++fc) {
      const int col = col0 + wn * 64 + fc * 32 + l31;
      const float bv = bias[col];
      const int rbase = row0 + wm * 128 + gm * 32 + 4 * hi;
      const f32x16 v = acc[gm][fc];
#pragma unroll
      for (int r = 0; r < 16; ++r) {
        const int row = rbase + (r & 3) + 8 * (r >> 2);
        C[(size_t)row * N + col] = v[r] + bv;
      }
    }
  }
#undef STAGE1
#undef LDA_
#undef LDB_
#undef MFMA_MH
}

// ---------------- fallback 128x128 GEMM (correctness safety net) ----------

template <bool XB16>
__global__ __launch_bounds__(256)
void gemm_kernel(const unsigned short* __restrict__ Abf,
                 const float* __restrict__ Af32,
                 const unsigned short* __restrict__ Bbf,
                 const float* __restrict__ bias,
                 float* __restrict__ C, int M, int N, int K)
{
  __shared__ unsigned short sA[128 * 64];
  __shared__ unsigned short sB[128 * 64];
  const int tid  = threadIdx.x;
  const int lane = tid & 63;
  const int wid  = tid >> 6;
  const int wm = wid >> 1, wn = wid & 1;
  const int ntn = N / 128;
  const int tm = blockIdx.x / ntn, tn = blockIdx.x - tm * ntn;
  const int row0 = tm * 128, col0 = tn * 128;

  f32x4 acc[4][4];
#pragma unroll
  for (int m = 0; m < 4; ++m)
#pragma unroll
    for (int n = 0; n < 4; ++n)
#pragma unroll
      for (int j = 0; j < 4; ++j) acc[m][n][j] = 0.0f;

  const int lrow = lane & 15;
  const int lko  = (lane >> 4) * 8;

  for (int k0 = 0; k0 < K; k0 += 64) {
    if (XB16) {
#pragma unroll
      for (int i = 0; i < 4; ++i) {
        const int wbase = i * 256 + (wid << 6);
        const int c = wbase + lane;
        const int r = c >> 3, ce = (c & 7) * 8;
        gload_lds16(sA + (size_t)wbase * 8, Abf + (size_t)(row0 + r) * K + k0 + ce);
      }
    } else {
#pragma unroll
      for (int i = 0; i < 4; ++i) {
        const int c = i * 256 + tid;
        const int r = c >> 3, ce = (c & 7) * 8;
        const float4* p = (const float4*)(Af32 + (size_t)(row0 + r) * K + k0 + ce);
        float4 aa = p[0], bb = p[1];
        u16x8 v;
        v[0] = f2bf(aa.x); v[1] = f2bf(aa.y); v[2] = f2bf(aa.z); v[3] = f2bf(aa.w);
        v[4] = f2bf(bb.x); v[5] = f2bf(bb.y); v[6] = f2bf(bb.z); v[7] = f2bf(bb.w);
        *(u16x8*)(sA + c * 8) = v;
      }
    }
#pragma unroll
    for (int i = 0; i < 4; ++i) {
      const int wbase = i * 256 + (wid << 6);
      const int c = wbase + lane;
      const int r = c >> 3, ce = (c & 7) * 8;
      gload_lds16(sB + (size_t)wbase * 8, Bbf + (size_t)(col0 + r) * K + k0 + ce);
    }
    __syncthreads();
    bf16x8 af[4][2], bfr[4][2];
#pragma unroll
    for (int m = 0; m < 4; ++m) {
      const int r = wm * 64 + m * 16 + lrow;
#pragma unroll
      for (int kk = 0; kk < 2; ++kk)
        af[m][kk] = *(const bf16x8*)(sA + r * 64 + kk * 32 + lko);
    }
#pragma unroll
    for (int n = 0; n < 4; ++n) {
      const int r = wn * 64 + n * 16 + lrow;
#pragma unroll
      for (int kk = 0; kk < 2; ++kk)
        bfr[n][kk] = *(const bf16x8*)(sB + r * 64 + kk * 32 + lko);
    }
#pragma unroll
    for (int kk = 0; kk < 2; ++kk)
#pragma unroll
      for (int m = 0; m < 4; ++m)
#pragma unroll
        for (int n = 0; n < 4; ++n)
          acc[m][n] = __builtin_amdgcn_mfma_f32_16x16x32_bf16(
              af[m][kk], bfr[n][kk], acc[m][n], 0, 0, 0);
    __syncthreads();
  }
#pragma unroll
  for (int n = 0; n < 4; ++n) {
    const int col = col0 + wn * 64 + n * 16 + lrow;
    const float bv = bias[col];
#pragma unroll
    for (int m = 0; m < 4; ++m) {
      const int row = row0 + wm * 64 + m * 16 + (lane >> 4) * 4;
      const f32x4 v = acc[m][n];
#pragma unroll
      for (int j = 0; j < 4; ++j)
        C[(size_t)(row + j) * N + col] = v[j] + bv;
    }
  }
}

// ---------------- host launch ----------------

extern "C" void kernel_launch(void* const* d_in, const int* in_sizes, int n_in,
                              void* d_out, int out_size, void* d_ws, size_t ws_size,
                              hipStream_t stream) {
  const float* x      = (const float*)d_in[0];
  const int* pw       = (const int*)d_in[1];     // uint8 widened to int32
  const float* scale  = (const float*)d_in[2];
  const float* zp     = (const float*)d_in[3];
  const float* bias   = (const float*)d_in[4];
  float* out = (float*)d_out;

  const int K = IN_F, N = OUT_F;
  const int M = in_sizes[0] / K;                 // 8192

  const size_t xbytes = (size_t)M * K * 2;       // 64 MiB
  const size_t wbytes = (size_t)N * K * 2;       // 32 MiB

  if (ws_size >= xbytes + wbytes && (M & 255) == 0) {
    unsigned short* Xb = (unsigned short*)d_ws;
    unsigned short* Wb = (unsigned short*)((char*)d_ws + xbytes);
    cvt_x_kernel<<<2048, 256, 0, stream>>>(x, Xb, (long)M * K / 8);
    dequant_w_kernel<<<(OUT_F / 2) * (IN_F / 8) / 256, 256, 0, stream>>>(pw, scale, zp, Wb);
    gemm256_kernel<<<(M / 256) * (N / 256), 512, 0, stream>>>(Xb, Wb, bias, out, M, N, K);
  } else if (ws_size >= xbytes + wbytes) {
    unsigned short* Xb = (unsigned short*)d_ws;
    unsigned short* Wb = (unsigned short*)((char*)d_ws + xbytes);
    cvt_x_kernel<<<2048, 256, 0, stream>>>(x, Xb, (long)M * K / 8);
    dequant_w_kernel<<<(OUT_F / 2) * (IN_F / 8) / 256, 256, 0, stream>>>(pw, scale, zp, Wb);
    gemm_kernel<true><<<(M / 128) * (N / 128), 256, 0, stream>>>(
        Xb, nullptr, Wb, bias, out, M, N, K);
  } else {
    unsigned short* Wb = (unsigned short*)d_ws;  // requires >= 32 MiB ws
    dequant_w_kernel<<<(OUT_F / 2) * (IN_F / 8) / 256, 256, 0, stream>>>(pw, scale, zp, Wb);
    gemm_kernel<false><<<(M / 128) * (N / 128), 256, 0, stream>>>(
        nullptr, x, Wb, bias, out, M, N, K);
  }
}

// Round 14
// 295.458 us; speedup vs baseline: 1.1873x; 1.0196x over previous
//
#include <hip/hip_runtime.h>
#include <stdint.h>

#define IN_F  4096
#define OUT_F 4096

typedef __attribute__((ext_vector_type(8))) short bf16x8;
typedef __attribute__((ext_vector_type(4))) float f32x4;
typedef __attribute__((ext_vector_type(16))) float f32x16;
typedef __attribute__((ext_vector_type(8))) unsigned short u16x8;

__device__ __forceinline__ unsigned short f2bf(float f) {
  union { float f; unsigned int u; } v; v.f = f;
  return (unsigned short)((v.u + 0x7FFFu + ((v.u >> 16) & 1u)) >> 16);
}

__device__ __forceinline__ void gload_lds16(void* lds, const void* g) {
  __builtin_amdgcn_global_load_lds((const __attribute__((address_space(1))) void*)g,
                                   (__attribute__((address_space(3))) void*)lds,
                                   16u, 0, 0u);
}

// ---------------- prep kernels ----------------

__global__ void cvt_x_kernel(const float* __restrict__ x,
                             unsigned short* __restrict__ o, long n8) {
  long i = (long)blockIdx.x * blockDim.x + threadIdx.x;
  long stride = (long)gridDim.x * blockDim.x;
  for (; i < n8; i += stride) {
    const float4* p = (const float4*)(x + i * 8);
    float4 a = p[0], b = p[1];
    u16x8 r;
    r[0] = f2bf(a.x); r[1] = f2bf(a.y); r[2] = f2bf(a.z); r[3] = f2bf(a.w);
    r[4] = f2bf(b.x); r[5] = f2bf(b.y); r[6] = f2bf(b.z); r[7] = f2bf(b.w);
    *(u16x8*)(o + i * 8) = r;
  }
}

// packed_weight arrives as int32 (harness widens uint8 -> int).
__global__ void dequant_w_kernel(const int* __restrict__ pw,
                                 const float* __restrict__ sp,
                                 const float* __restrict__ zpp,
                                 unsigned short* __restrict__ W) {
  const float scale = *sp, zp = *zpp;
  int i = blockIdx.x * blockDim.x + threadIdx.x;
  const int total = (OUT_F / 2) * (IN_F / 8);
  if (i >= total) return;
  int r = i / (IN_F / 8);
  int c = (i - r * (IN_F / 8)) * 8;
  const int* src = pw + (size_t)r * IN_F + c;
  int4 p0 = *(const int4*)(src);
  int4 p1 = *(const int4*)(src + 4);
  int bytes[8] = { p0.x, p0.y, p0.z, p0.w, p1.x, p1.y, p1.z, p1.w };
  u16x8 lo, hi;
#pragma unroll
  for (int j = 0; j < 8; ++j) {
    unsigned int b = (unsigned int)bytes[j] & 0xFFu;
    lo[j] = f2bf(scale * ((float)(b & 15u) - zp));
    hi[j] = f2bf(scale * ((float)(b >> 4) - zp));
  }
  *(u16x8*)(W + (size_t)(2 * r) * IN_F + c) = lo;
  *(u16x8*)(W + (size_t)(2 * r + 1) * IN_F + c) = hi;
}

// ====== 256x256 GEMM, 32x32x16 MFMA, 4-zone/iter, RACE-FIXED stages ========
// r12 base (verified): gt-swizzled LDS, linear gload dest + pre-swizzled src,
// A frag row=lane&31 k-half=lane>>5, C/D col=lane&31 row=(r&3)+8*(r>>2)+4*hi.
// Zone = one mh-half x BOTH nh -> 16 MFMA over 4 accs (distance 4).
//
// CROSS-WAVE RAW RULE (r13's race): vmcnt is PER-WAVE; a stage read by other
// waves at zone k must be drained by a VM that every wave executes BEFORE the
// barrier at k. With per-zone VM at zone start, that means stage at j, read
// at k needs j <= k-3. Schedule (verified by FIFO simulation, groups [2,6,2,6],
// VM [6,2,6,2], max outstanding 8):
//   Z1: reads b0 A0 + B(U,V); stages b1A q1,q3 (T+1)      [2]  read Z4 (d3)
//   Z2: reads b0 A1;          stages b0B q0-q3 + A q0,q2 (T+2)[6] read Z1' (d3)
//   Z3: reads b1 A0'+ B'(U,V);stages b0A q1,q3 (T+2)      [2]  read Z2' (d3)
//   Z4: reads b1 A1';         stages b1A q0,q2 + B q0-q3 (T+3)[6] read Z3' (d3)
// Guard chain: VM@Z4(2) drains g(Z2) before BAR(Z1'); VM@Z1'(6) drains g(Z3);
// VM@Z2(2) drains g(Z4@prev); VM@Z3(6) drains g(Z1). WAR: every staged region
// last read exactly 1 zone earlier (same-zone-consume + barrier rule).
// Prologue: 14 loads + VM(6) BEFORE first barrier (formal iter-0 guarantee).

#define BAR()   __builtin_amdgcn_s_barrier()
#define SB0()   __builtin_amdgcn_sched_barrier(0)
#define VM(n)   asm volatile("s_waitcnt vmcnt(" #n ")")

__global__ __launch_bounds__(512, 2)
void gemm256_kernel(const unsigned short* __restrict__ A,
                    const unsigned short* __restrict__ B,
                    const float* __restrict__ bias,
                    float* __restrict__ C, int M, int N, int K)
{
  __shared__ unsigned short sA[2 * 16384];   // [buf][4 quarters][64r x 8ch] gt-swz
  __shared__ unsigned short sB[2 * 16384];

  const int tid  = threadIdx.x;
  const int lane = tid & 63;
  const int wid  = tid >> 6;          // 0..7
  const int wm   = wid >> 2;          // 0..1
  const int wn   = wid & 3;           // 0..3

  // T1: XCD-aware bijective swizzle (grid = 512 = 8*64)
  const int cpx = gridDim.x >> 3;
  const int swz = ((int)blockIdx.x & 7) * cpx + ((int)blockIdx.x >> 3);
  const int ntn = N >> 8;
  const int tm = swz / ntn, tn = swz - tm * ntn;
  const int row0 = tm << 8, col0 = tn << 8;

  const int l31  = lane & 31;
  const int hi   = lane >> 5;                    // 0..1 k-half
  const int X0   = (lane & 7) ^ ((lane >> 3) & 3);
  const int aRow = l31 << 6;                     // (lane&31)*64 elements

  // staging: linear dest unit t=tid; holds row t>>3, stored-chunk t&7 ->
  // logical chunk = sc ^ (row&7) ^ ((row>>3)&7)
  const int srow   = tid >> 3;                   // 0..63 within quarter
  const int schunk = (tid & 7) ^ (srow & 7) ^ ((srow >> 3) & 7);

  f32x16 acc[4][2];
#pragma unroll
  for (int m = 0; m < 4; ++m)
#pragma unroll
    for (int n = 0; n < 2; ++n)
#pragma unroll
      for (int j = 0; j < 16; ++j) acc[m][n][j] = 0.0f;

  bf16x8 a[2][4];                 // A slot [fr][ks] (same-zone consume)
  bf16x8 U[4], V[4];              // B slots nh0 / nh1 [ks]

  // one 8 KiB quarter (64 rows x 64 K-elems) per gload
#define STAGE1(arr, buf, q, gbase, kt) \
    gload_lds16(arr + (buf)*16384 + (q)*4096 + wid*512, \
        (gbase) + (size_t)((q)*64 + srow) * K + (kt)*64 + schunk*8)

#define LDA_(buf, mh) do {                                                    \
    _Pragma("unroll")                                                         \
    for (int fr = 0; fr < 2; ++fr)                                            \
      _Pragma("unroll")                                                       \
      for (int ks = 0; ks < 4; ++ks) {                                        \
        const int off_ = (buf)*16384 + (wm*2 + (mh))*4096 + fr*2048 + aRow    \
            + ((((ks*2 + hi) ^ X0 ^ (fr << 2)) & 7) << 3);                    \
        a[fr][ks] = *(const bf16x8*)(sA + off_);                              \
      } } while (0)

  // read BOTH B halves: nh0 -> U, nh1 -> V (8 x ds_read_b128)
#define LDB2_(buf) do {                                                       \
    _Pragma("unroll")                                                         \
    for (int ks = 0; ks < 4; ++ks) {                                          \
      const int offU = (buf)*16384 + wn*4096 + aRow                           \
          + ((((ks*2 + hi) ^ X0) & 7) << 3);                                  \
      U[ks] = *(const bf16x8*)(sB + offU);                                    \
      const int offV = (buf)*16384 + wn*4096 + 2048 + aRow                    \
          + ((((ks*2 + hi) ^ X0 ^ 4) & 7) << 3);                              \
      V[ks] = *(const bf16x8*)(sB + offV);                                    \
    } } while (0)

  // 16 MFMA 32x32x16 over 4 accs (distance-4: ks{fr{nh{}}})
#define MFMA_Z(MH) do {                                                       \
    __builtin_amdgcn_s_setprio(1);                                            \
    _Pragma("unroll")                                                         \
    for (int ks = 0; ks < 4; ++ks)                                            \
      _Pragma("unroll")                                                       \
      for (int fr = 0; fr < 2; ++fr) {                                        \
        acc[(MH)*2+fr][0] = __builtin_amdgcn_mfma_f32_32x32x16_bf16(          \
            a[fr][ks], U[ks], acc[(MH)*2+fr][0], 0, 0, 0);                    \
        acc[(MH)*2+fr][1] = __builtin_amdgcn_mfma_f32_32x32x16_bf16(          \
            a[fr][ks], V[ks], acc[(MH)*2+fr][1], 0, 0, 0);                    \
      }                                                                       \
    __builtin_amdgcn_s_setprio(0);                                            \
  } while (0)

  const unsigned short* Ag = A + (size_t)row0 * K;
  const unsigned short* Bg = B + (size_t)col0 * K;

  // ---- prologue: 14 gloads (virtual Z2/Z3/Z4 of iter -1), then VM(6)
  //      BEFORE the first barrier so iter-0 reads are formally guarded ----
  STAGE1(sB, 0, 0, Bg, 0); STAGE1(sB, 0, 1, Bg, 0);   // vZ2: b0B q0,q1
  STAGE1(sB, 0, 2, Bg, 0); STAGE1(sB, 0, 3, Bg, 0);   //      b0B q2,q3
  STAGE1(sA, 0, 0, Ag, 0); STAGE1(sA, 0, 2, Ag, 0);   //      b0A q0,q2
  STAGE1(sA, 0, 1, Ag, 0); STAGE1(sA, 0, 3, Ag, 0);   // vZ3: b0A q1,q3
  STAGE1(sA, 1, 0, Ag, 1); STAGE1(sA, 1, 2, Ag, 1);   // vZ4: b1A q0,q2
  STAGE1(sB, 1, 0, Bg, 1); STAGE1(sB, 1, 1, Bg, 1);   //      b1B q0,q1
  STAGE1(sB, 1, 2, Bg, 1); STAGE1(sB, 1, 3, Bg, 1);   //      b1B q2,q3
  SB0(); VM(6); SB0();      // drains vZ2+vZ3 (b0 complete) in EVERY wave
                            // before any wave passes the first barrier

  const int nkt = K >> 6;               // 64 K-tiles
  const int nit = nkt >> 1;             // 32 iterations
  for (int it = 0; it < nit; ++it) {
    const int T  = 2 * it;
    const int t1 = T + 1;                             // <= 63 always (real)
    const int k2 = (T + 2 < nkt) ? T + 2 : nkt - 1;   // clamp: benign regions
    const int k3 = (T + 3 < nkt) ? T + 3 : nkt - 1;
    // Z1: tile T, mh0. reads b0 A0 + B(U,V); stage b1A q1,q3 (T+1)  [2]
    BAR(); SB0(); VM(6); SB0();
    LDA_(0, 0);
    LDB2_(0);
    STAGE1(sA, 1, 1, Ag, t1); STAGE1(sA, 1, 3, Ag, t1);
    MFMA_Z(0);
    // Z2: tile T, mh1. reads b0 A1; stage b0B q0-q3 + b0A q0,q2 (T+2) [6]
    BAR(); SB0(); VM(2); SB0();
    LDA_(0, 1);
    STAGE1(sB, 0, 0, Bg, k2); STAGE1(sB, 0, 1, Bg, k2);
    STAGE1(sB, 0, 2, Bg, k2); STAGE1(sB, 0, 3, Bg, k2);
    STAGE1(sA, 0, 0, Ag, k2); STAGE1(sA, 0, 2, Ag, k2);
    MFMA_Z(1);
    // Z3: tile T+1, mh0. reads b1 A0' + B'(U,V); stage b0A q1,q3 (T+2) [2]
    BAR(); SB0(); VM(6); SB0();
    LDA_(1, 0);
    LDB2_(1);
    STAGE1(sA, 0, 1, Ag, k2); STAGE1(sA, 0, 3, Ag, k2);
    MFMA_Z(0);
    // Z4: tile T+1, mh1. reads b1 A1'; stage b1A q0,q2 + b1B q0-q3 (T+3) [6]
    BAR(); SB0(); VM(2); SB0();
    LDA_(1, 1);
    STAGE1(sA, 1, 0, Ag, k3); STAGE1(sA, 1, 2, Ag, k3);
    STAGE1(sB, 1, 0, Bg, k3); STAGE1(sB, 1, 1, Bg, k3);
    STAGE1(sB, 1, 2, Bg, k3); STAGE1(sB, 1, 3, Bg, k3);
    MFMA_Z(1);
  }

  asm volatile("s_waitcnt vmcnt(0)" ::: "memory");  // drain trailing stages

  // ---- epilogue: 32x32 C/D mapping (col=lane&31, row=(r&3)+8*(r>>2)+4*hi) --
#pragma unroll
  for (int gm = 0; gm < 4; ++gm) {
#pragma unroll
    for (int fc = 0; fc < 2; ++fc) {
      const int col = col0 + wn * 64 + fc * 32 + l31;
      const float bv = bias[col];
      const int rbase = row0 + wm * 128 + gm * 32 + 4 * hi;
      const f32x16 v = acc[gm][fc];
#pragma unroll
      for (int r = 0; r < 16; ++r) {
        const int row = rbase + (r & 3) + 8 * (r >> 2);
        C[(size_t)row * N + col] = v[r] + bv;
      }
    }
  }
#undef STAGE1
#undef LDA_
#undef LDB2_
#undef MFMA_Z
}

// ---------------- fallback 128x128 GEMM (correctness safety net) ----------

template <bool XB16>
__global__ __launch_bounds__(256)
void gemm_kernel(const unsigned short* __restrict__ Abf,
                 const float* __restrict__ Af32,
                 const unsigned short* __restrict__ Bbf,
                 const float* __restrict__ bias,
                 float* __restrict__ C, int M, int N, int K)
{
  __shared__ unsigned short sA[128 * 64];
  __shared__ unsigned short sB[128 * 64];
  const int tid  = threadIdx.x;
  const int lane = tid & 63;
  const int wid  = tid >> 6;
  const int wm = wid >> 1, wn = wid & 1;
  const int ntn = N / 128;
  const int tm = blockIdx.x / ntn, tn = blockIdx.x - tm * ntn;
  const int row0 = tm * 128, col0 = tn * 128;

  f32x4 acc[4][4];
#pragma unroll
  for (int m = 0; m < 4; ++m)
#pragma unroll
    for (int n = 0; n < 4; ++n)
#pragma unroll
      for (int j = 0; j < 4; ++j) acc[m][n][j] = 0.0f;

  const int lrow = lane & 15;
  const int lko  = (lane >> 4) * 8;

  for (int k0 = 0; k0 < K; k0 += 64) {
    if (XB16) {
#pragma unroll
      for (int i = 0; i < 4; ++i) {
        const int wbase = i * 256 + (wid << 6);
        const int c = wbase + lane;
        const int r = c >> 3, ce = (c & 7) * 8;
        gload_lds16(sA + (size_t)wbase * 8, Abf + (size_t)(row0 + r) * K + k0 + ce);
      }
    } else {
#pragma unroll
      for (int i = 0; i < 4; ++i) {
        const int c = i * 256 + tid;
        const int r = c >> 3, ce = (c & 7) * 8;
        const float4* p = (const float4*)(Af32 + (size_t)(row0 + r) * K + k0 + ce);
        float4 aa = p[0], bb = p[1];
        u16x8 v;
        v[0] = f2bf(aa.x); v[1] = f2bf(aa.y); v[2] = f2bf(aa.z); v[3] = f2bf(aa.w);
        v[4] = f2bf(bb.x); v[5] = f2bf(bb.y); v[6] = f2bf(bb.z); v[7] = f2bf(bb.w);
        *(u16x8*)(sA + c * 8) = v;
      }
    }
#pragma unroll
    for (int i = 0; i < 4; ++i) {
      const int wbase = i * 256 + (wid << 6);
      const int c = wbase + lane;
      const int r = c >> 3, ce = (c & 7) * 8;
      gload_lds16(sB + (size_t)wbase * 8, Bbf + (size_t)(col0 + r) * K + k0 + ce);
    }
    __syncthreads();
    bf16x8 af[4][2], bfr[4][2];
#pragma unroll
    for (int m = 0; m < 4; ++m) {
      const int r = wm * 64 + m * 16 + lrow;
#pragma unroll
      for (int kk = 0; kk < 2; ++kk)
        af[m][kk] = *(const bf16x8*)(sA + r * 64 + kk * 32 + lko);
    }
#pragma unroll
    for (int n = 0; n < 4; ++n) {
      const int r = wn * 64 + n * 16 + lrow;
#pragma unroll
      for (int kk = 0; kk < 2; ++kk)
        bfr[n][kk] = *(const bf16x8*)(sB + r * 64 + kk * 32 + lko);
    }
#pragma unroll
    for (int kk = 0; kk < 2; ++kk)
#pragma unroll
      for (int m = 0; m < 4; ++m)
#pragma unroll
        for (int n = 0; n < 4; ++n)
          acc[m][n] = __builtin_amdgcn_mfma_f32_16x16x32_bf16(
              af[m][kk], bfr[n][kk], acc[m][n], 0, 0, 0);
    __syncthreads();
  }
#pragma unroll
  for (int n = 0; n < 4; ++n) {
    const int col = col0 + wn * 64 + n * 16 + lrow;
    const float bv = bias[col];
#pragma unroll
    for (int m = 0; m < 4; ++m) {
      const int row = row0 + wm * 64 + m * 16 + (lane >> 4) * 4;
      const f32x4 v = acc[m][n];
#pragma unroll
      for (int j = 0; j < 4; ++j)
        C[(size_t)(row + j) * N + col] = v[j] + bv;
    }
  }
}

// ---------------- host launch ----------------

extern "C" void kernel_launch(void* const* d_in, const int* in_sizes, int n_in,
                              void* d_out, int out_size, void* d_ws, size_t ws_size,
                              hipStream_t stream) {
  const float* x      = (const float*)d_in[0];
  const int* pw       = (const int*)d_in[1];     // uint8 widened to int32
  const float* scale  = (const float*)d_in[2];
  const float* zp     = (const float*)d_in[3];
  const float* bias   = (const float*)d_in[4];
  float* out = (float*)d_out;

  const int K = IN_F, N = OUT_F;
  const int M = in_sizes[0] / K;                 // 8192

  const size_t xbytes = (size_t)M * K * 2;       // 64 MiB
  const size_t wbytes = (size_t)N * K * 2;       // 32 MiB

  if (ws_size >= xbytes + wbytes && (M & 255) == 0) {
    unsigned short* Xb = (unsigned short*)d_ws;
    unsigned short* Wb = (unsigned short*)((char*)d_ws + xbytes);
    cvt_x_kernel<<<2048, 256, 0, stream>>>(x, Xb, (long)M * K / 8);
    dequant_w_kernel<<<(OUT_F / 2) * (IN_F / 8) / 256, 256, 0, stream>>>(pw, scale, zp, Wb);
    gemm256_kernel<<<(M / 256) * (N / 256), 512, 0, stream>>>(Xb, Wb, bias, out, M, N, K);
  } else if (ws_size >= xbytes + wbytes) {
    unsigned short* Xb = (unsigned short*)d_ws;
    unsigned short* Wb = (unsigned short*)((char*)d_ws + xbytes);
    cvt_x_kernel<<<2048, 256, 0, stream>>>(x, Xb, (long)M * K / 8);
    dequant_w_kernel<<<(OUT_F / 2) * (IN_F / 8) / 256, 256, 0, stream>>>(pw, scale, zp, Wb);
    gemm_kernel<true><<<(M / 128) * (N / 128), 256, 0, stream>>>(
        Xb, nullptr, Wb, bias, out, M, N, K);
  } else {
    unsigned short* Wb = (unsigned short*)d_ws;  // requires >= 32 MiB ws
    dequant_w_kernel<<<(OUT_F / 2) * (IN_F / 8) / 256, 256, 0, stream>>>(pw, scale, zp, Wb);
    gemm_kernel<false><<<(M / 128) * (N / 128), 256, 0, stream>>>(
        nullptr, x, Wb, bias, out, M, N, K);
  }
}

// Round 15
// 179.744 us; speedup vs baseline: 1.9516x; 1.6438x over previous
//
#include <hip/hip_runtime.h>
#include <stdint.h>

#define IN_F  4096
#define OUT_F 4096

typedef __attribute__((ext_vector_type(8))) short bf16x8;
typedef __attribute__((ext_vector_type(4))) float f32x4;
typedef __attribute__((ext_vector_type(4))) int   i32x4;
typedef __attribute__((ext_vector_type(16))) int  i32x16;
typedef __attribute__((ext_vector_type(8))) unsigned short u16x8;

__device__ __forceinline__ unsigned short f2bf(float f) {
  union { float f; unsigned int u; } v; v.f = f;
  return (unsigned short)((v.u + 0x7FFFu + ((v.u >> 16) & 1u)) >> 16);
}

__device__ __forceinline__ void gload_lds16(void* lds, const void* g) {
  __builtin_amdgcn_global_load_lds((const __attribute__((address_space(1))) void*)g,
                                   (__attribute__((address_space(3))) void*)lds,
                                   16u, 0, 0u);
}

// ---------------- prep kernels (i8 path) ----------------

// Per-row symmetric int8 quantization of X: xi = rint(x / (rowmax/127)),
// plus per-row sum of xi. One block per row (256 thr, 16 floats/thread).
__global__ __launch_bounds__(256)
void quant_x_kernel(const float* __restrict__ x,
                    signed char* __restrict__ xq,
                    float* __restrict__ sx, int* __restrict__ rsum) {
  const int row = blockIdx.x;
  const int tid = threadIdx.x;
  const int lane = tid & 63, wid = tid >> 6;
  const float4* src = (const float4*)(x + (size_t)row * 4096);
  float4 v[4];
#pragma unroll
  for (int j = 0; j < 4; ++j) v[j] = src[tid * 4 + j];
  float amax = 0.f;
#pragma unroll
  for (int j = 0; j < 4; ++j) {
    amax = fmaxf(amax, fmaxf(fmaxf(fabsf(v[j].x), fabsf(v[j].y)),
                             fmaxf(fabsf(v[j].z), fabsf(v[j].w))));
  }
#pragma unroll
  for (int off = 32; off > 0; off >>= 1)
    amax = fmaxf(amax, __shfl_xor(amax, off));
  __shared__ float wmax[4];
  __shared__ int wsum[4];
  if (lane == 0) wmax[wid] = amax;
  __syncthreads();
  amax = fmaxf(fmaxf(wmax[0], wmax[1]), fmaxf(wmax[2], wmax[3]));
  const float s   = (amax > 0.f) ? amax / 127.f : 1.f;
  const float inv = (amax > 0.f) ? 127.f / amax : 0.f;
  int sum = 0, pk[4];
#pragma unroll
  for (int j = 0; j < 4; ++j) {
    float e[4] = { v[j].x, v[j].y, v[j].z, v[j].w };
    int b[4];
#pragma unroll
    for (int c = 0; c < 4; ++c) {
      int q = (int)rintf(e[c] * inv);
      q = q > 127 ? 127 : (q < -127 ? -127 : q);
      sum += q;
      b[c] = q & 255;
    }
    pk[j] = b[0] | (b[1] << 8) | (b[2] << 16) | (b[3] << 24);
  }
  int4 w = { pk[0], pk[1], pk[2], pk[3] };
  ((int4*)xq)[(size_t)row * 256 + tid] = w;
#pragma unroll
  for (int off = 32; off > 0; off >>= 1) sum += __shfl_xor(sum, off);
  if (lane == 0) wsum[wid] = sum;
  __syncthreads();
  if (tid == 0) { sx[row] = s; rsum[row] = wsum[0] + wsum[1] + wsum[2] + wsum[3]; }
}

// Unpack 4-bit nibbles (int32-widened bytes) to i8 Q matrix (0..15).
__global__ void unpack_w_kernel(const int* __restrict__ pw,
                                signed char* __restrict__ Wq) {
  int i = blockIdx.x * blockDim.x + threadIdx.x;
  const int total = (OUT_F / 2) * (IN_F / 8);
  if (i >= total) return;
  int r = i / (IN_F / 8);
  int c = (i - r * (IN_F / 8)) * 8;
  const int* src = pw + (size_t)r * IN_F + c;
  int4 p0 = *(const int4*)(src);
  int4 p1 = *(const int4*)(src + 4);
  int bytes[8] = { p0.x, p0.y, p0.z, p0.w, p1.x, p1.y, p1.z, p1.w };
  unsigned int lo0 = 0, lo1 = 0, hi0 = 0, hi1 = 0;
#pragma unroll
  for (int j = 0; j < 4; ++j) {
    unsigned int b = (unsigned int)bytes[j] & 0xFFu;
    lo0 |= (b & 15u) << (8 * j);
    hi0 |= (b >> 4) << (8 * j);
  }
#pragma unroll
  for (int j = 0; j < 4; ++j) {
    unsigned int b = (unsigned int)bytes[4 + j] & 0xFFu;
    lo1 |= (b & 15u) << (8 * j);
    hi1 |= (b >> 4) << (8 * j);
  }
  uint2 lo = { lo0, lo1 }, hi = { hi0, hi1 };
  *(uint2*)(Wq + (size_t)(2 * r) * IN_F + c) = lo;
  *(uint2*)(Wq + (size_t)(2 * r + 1) * IN_F + c) = hi;
}

// ====== 256x256 GEMM, i8 mfma_i32_32x32x32 (2x bf16 rate, half bytes) ======
// EXACT r14 schedule (hardware-verified, race-free): 4 zones/iter, stage
// groups [2,6,2,6], VM [6,2,6,2], 14-load prologue + VM(6) before first
// barrier, cross-wave RAW distance >= 3 zones, same-zone-consume WAR rule.
// BK=128 i8 (128 B rows -> identical 8-chunk gt-swizzle geometry as bf16).
// Exact integer math: y = sx[r]*scale*(dot - zp*rsum[r]) + bias[c].
// A frag: row=lane&31, k=(lane>>5)*16+e (16B contiguous, analog of verified
// bf16 32x32 mapping). C/D: col=lane&31, row=(r&3)+8*(r>>2)+4*(lane>>5)
// (shape-determined, dtype-independent per m101/m127).

#define BAR()   __builtin_amdgcn_s_barrier()
#define SB0()   __builtin_amdgcn_sched_barrier(0)
#define VM(n)   asm volatile("s_waitcnt vmcnt(" #n ")")

__global__ __launch_bounds__(512, 2)
void gemm256_i8_kernel(const signed char* __restrict__ A,
                       const signed char* __restrict__ B,
                       const float* __restrict__ sx,
                       const int* __restrict__ rsum,
                       const float* __restrict__ sp,
                       const float* __restrict__ zpp,
                       const float* __restrict__ bias,
                       float* __restrict__ C, int M, int N, int K)
{
  __shared__ signed char sA[2 * 32768];   // [buf][4 quarters][64r x 128B] gt-swz
  __shared__ signed char sB[2 * 32768];

  const int tid  = threadIdx.x;
  const int lane = tid & 63;
  const int wid  = tid >> 6;          // 0..7
  const int wm   = wid >> 2;          // 0..1
  const int wn   = wid & 3;           // 0..3

  const float scaleV = *sp, zpV = *zpp;

  // T1: XCD-aware bijective swizzle (grid = 512 = 8*64)
  const int cpx = gridDim.x >> 3;
  const int swz = ((int)blockIdx.x & 7) * cpx + ((int)blockIdx.x >> 3);
  const int ntn = N >> 8;
  const int tm = swz / ntn, tn = swz - tm * ntn;
  const int row0 = tm << 8, col0 = tn << 8;

  const int l31  = lane & 31;
  const int hi   = lane >> 5;                    // 0..1 k-half (16 B)
  const int X0   = (lane & 7) ^ ((lane >> 3) & 3);

  // staging: linear dest unit t=tid (16 B); holds row t>>3, stored-chunk t&7
  // -> logical chunk = sc ^ (row&7) ^ ((row>>3)&7)
  const int srow   = tid >> 3;                   // 0..63 within quarter
  const int schunk = (tid & 7) ^ (srow & 7) ^ ((srow >> 3) & 7);

  i32x16 acc[4][2];
#pragma unroll
  for (int m = 0; m < 4; ++m)
#pragma unroll
    for (int n = 0; n < 2; ++n)
#pragma unroll
      for (int j = 0; j < 16; ++j) acc[m][n][j] = 0;

  i32x4 a[2][4];                 // A slot [fr][ks] (same-zone consume)
  i32x4 U[4], V[4];              // B slots nh0 / nh1 [ks]

  // one 8 KiB quarter (64 rows x 128 B) per gload
#define STAGE1(arr, buf, q, gbase, kt) \
    gload_lds16(arr + (buf)*32768 + (q)*8192 + tid*16, \
        (gbase) + (size_t)((q)*64 + srow) * K + (kt)*128 + schunk*16)

#define LDA_(buf, mh) do {                                                    \
    _Pragma("unroll")                                                         \
    for (int fr = 0; fr < 2; ++fr)                                            \
      _Pragma("unroll")                                                       \
      for (int ks = 0; ks < 4; ++ks) {                                        \
        const int off_ = (buf)*32768 + (wm*2 + (mh))*8192 + fr*4096           \
            + l31*128 + ((((ks*2 + hi) ^ X0 ^ (fr << 2)) & 7) << 4);          \
        a[fr][ks] = *(const i32x4*)(sA + off_);                               \
      } } while (0)

  // read BOTH B halves: nh0 -> U, nh1 -> V (8 x ds_read_b128)
#define LDB2_(buf) do {                                                       \
    _Pragma("unroll")                                                         \
    for (int ks = 0; ks < 4; ++ks) {                                          \
      const int offU = (buf)*32768 + wn*8192 + l31*128                        \
          + ((((ks*2 + hi) ^ X0) & 7) << 4);                                  \
      U[ks] = *(const i32x4*)(sB + offU);                                     \
      const int offV = (buf)*32768 + wn*8192 + 4096 + l31*128                 \
          + ((((ks*2 + hi) ^ X0 ^ 4) & 7) << 4);                              \
      V[ks] = *(const i32x4*)(sB + offV);                                     \
    } } while (0)

  // 16 MFMA i32_32x32x32_i8 over 4 accs (distance-4: ks{fr{nh{}}})
#define MFMA_Z(MH) do {                                                       \
    __builtin_amdgcn_s_setprio(1);                                            \
    _Pragma("unroll")                                                         \
    for (int ks = 0; ks < 4; ++ks)                                            \
      _Pragma("unroll")                                                       \
      for (int fr = 0; fr < 2; ++fr) {                                        \
        acc[(MH)*2+fr][0] = __builtin_amdgcn_mfma_i32_32x32x32_i8(            \
            a[fr][ks], U[ks], acc[(MH)*2+fr][0], 0, 0, 0);                    \
        acc[(MH)*2+fr][1] = __builtin_amdgcn_mfma_i32_32x32x32_i8(            \
            a[fr][ks], V[ks], acc[(MH)*2+fr][1], 0, 0, 0);                    \
      }                                                                       \
    __builtin_amdgcn_s_setprio(0);                                            \
  } while (0)

  const signed char* Ag = A + (size_t)row0 * K;
  const signed char* Bg = B + (size_t)col0 * K;

  // ---- prologue: 14 gloads (virtual Z2/Z3/Z4 of iter -1), then VM(6)
  //      BEFORE the first barrier so iter-0 reads are formally guarded ----
  STAGE1(sB, 0, 0, Bg, 0); STAGE1(sB, 0, 1, Bg, 0);   // vZ2: b0B q0,q1
  STAGE1(sB, 0, 2, Bg, 0); STAGE1(sB, 0, 3, Bg, 0);   //      b0B q2,q3
  STAGE1(sA, 0, 0, Ag, 0); STAGE1(sA, 0, 2, Ag, 0);   //      b0A q0,q2
  STAGE1(sA, 0, 1, Ag, 0); STAGE1(sA, 0, 3, Ag, 0);   // vZ3: b0A q1,q3
  STAGE1(sA, 1, 0, Ag, 1); STAGE1(sA, 1, 2, Ag, 1);   // vZ4: b1A q0,q2
  STAGE1(sB, 1, 0, Bg, 1); STAGE1(sB, 1, 1, Bg, 1);   //      b1B q0,q1
  STAGE1(sB, 1, 2, Bg, 1); STAGE1(sB, 1, 3, Bg, 1);   //      b1B q2,q3
  SB0(); VM(6); SB0();      // drains vZ2+vZ3 (b0 complete) in EVERY wave
                            // before any wave passes the first barrier

  const int nkt = K >> 7;               // 32 K-tiles of 128
  const int nit = nkt >> 1;             // 16 iterations
  for (int it = 0; it < nit; ++it) {
    const int T  = 2 * it;
    const int t1 = T + 1;                             // <= 31 always (real)
    const int k2 = (T + 2 < nkt) ? T + 2 : nkt - 1;   // clamp: benign regions
    const int k3 = (T + 3 < nkt) ? T + 3 : nkt - 1;
    // Z1: tile T, mh0. reads b0 A0 + B(U,V); stage b1A q1,q3 (T+1)  [2]
    BAR(); SB0(); VM(6); SB0();
    LDA_(0, 0);
    LDB2_(0);
    STAGE1(sA, 1, 1, Ag, t1); STAGE1(sA, 1, 3, Ag, t1);
    MFMA_Z(0);
    // Z2: tile T, mh1. reads b0 A1; stage b0B q0-q3 + b0A q0,q2 (T+2) [6]
    BAR(); SB0(); VM(2); SB0();
    LDA_(0, 1);
    STAGE1(sB, 0, 0, Bg, k2); STAGE1(sB, 0, 1, Bg, k2);
    STAGE1(sB, 0, 2, Bg, k2); STAGE1(sB, 0, 3, Bg, k2);
    STAGE1(sA, 0, 0, Ag, k2); STAGE1(sA, 0, 2, Ag, k2);
    MFMA_Z(1);
    // Z3: tile T+1, mh0. reads b1 A0' + B'(U,V); stage b0A q1,q3 (T+2) [2]
    BAR(); SB0(); VM(6); SB0();
    LDA_(1, 0);
    LDB2_(1);
    STAGE1(sA, 0, 1, Ag, k2); STAGE1(sA, 0, 3, Ag, k2);
    MFMA_Z(0);
    // Z4: tile T+1, mh1. reads b1 A1'; stage b1A q0,q2 + b1B q0-q3 (T+3) [6]
    BAR(); SB0(); VM(2); SB0();
    LDA_(1, 1);
    STAGE1(sA, 1, 0, Ag, k3); STAGE1(sA, 1, 2, Ag, k3);
    STAGE1(sB, 1, 0, Bg, k3); STAGE1(sB, 1, 1, Bg, k3);
    STAGE1(sB, 1, 2, Bg, k3); STAGE1(sB, 1, 3, Bg, k3);
    MFMA_Z(1);
  }

  asm volatile("s_waitcnt vmcnt(0)" ::: "memory");  // drain trailing stages

  // ---- epilogue: y = sx[r]*scale*(dot - zp*rsum[r]) + bias[c] ----
  const float bv0 = bias[col0 + wn * 64 + l31];
  const float bv1 = bias[col0 + wn * 64 + 32 + l31];
#pragma unroll
  for (int gm = 0; gm < 4; ++gm) {
    const int rbase = row0 + wm * 128 + gm * 32 + 4 * hi;
#pragma unroll
    for (int r = 0; r < 16; ++r) {
      const int row = rbase + (r & 3) + 8 * (r >> 2);
      const float sr   = sx[row] * scaleV;
      const float corr = zpV * (float)rsum[row];
      const int col = col0 + wn * 64 + l31;
      C[(size_t)row * N + col]      = sr * ((float)acc[gm][0][r] - corr) + bv0;
      C[(size_t)row * N + col + 32] = sr * ((float)acc[gm][1][r] - corr) + bv1;
    }
  }
#undef STAGE1
#undef LDA_
#undef LDB2_
#undef MFMA_Z
}

// ---------------- bf16 fallback chain (unchanged, safety net) -------------

__global__ void cvt_x_kernel(const float* __restrict__ x,
                             unsigned short* __restrict__ o, long n8) {
  long i = (long)blockIdx.x * blockDim.x + threadIdx.x;
  long stride = (long)gridDim.x * blockDim.x;
  for (; i < n8; i += stride) {
    const float4* p = (const float4*)(x + i * 8);
    float4 a = p[0], b = p[1];
    u16x8 r;
    r[0] = f2bf(a.x); r[1] = f2bf(a.y); r[2] = f2bf(a.z); r[3] = f2bf(a.w);
    r[4] = f2bf(b.x); r[5] = f2bf(b.y); r[6] = f2bf(b.z); r[7] = f2bf(b.w);
    *(u16x8*)(o + i * 8) = r;
  }
}

__global__ void dequant_w_kernel(const int* __restrict__ pw,
                                 const float* __restrict__ sp,
                                 const float* __restrict__ zpp,
                                 unsigned short* __restrict__ W) {
  const float scale = *sp, zp = *zpp;
  int i = blockIdx.x * blockDim.x + threadIdx.x;
  const int total = (OUT_F / 2) * (IN_F / 8);
  if (i >= total) return;
  int r = i / (IN_F / 8);
  int c = (i - r * (IN_F / 8)) * 8;
  const int* src = pw + (size_t)r * IN_F + c;
  int4 p0 = *(const int4*)(src);
  int4 p1 = *(const int4*)(src + 4);
  int bytes[8] = { p0.x, p0.y, p0.z, p0.w, p1.x, p1.y, p1.z, p1.w };
  u16x8 lo, hi;
#pragma unroll
  for (int j = 0; j < 8; ++j) {
    unsigned int b = (unsigned int)bytes[j] & 0xFFu;
    lo[j] = f2bf(scale * ((float)(b & 15u) - zp));
    hi[j] = f2bf(scale * ((float)(b >> 4) - zp));
  }
  *(u16x8*)(W + (size_t)(2 * r) * IN_F + c) = lo;
  *(u16x8*)(W + (size_t)(2 * r + 1) * IN_F + c) = hi;
}

template <bool XB16>
__global__ __launch_bounds__(256)
void gemm_kernel(const unsigned short* __restrict__ Abf,
                 const float* __restrict__ Af32,
                 const unsigned short* __restrict__ Bbf,
                 const float* __restrict__ bias,
                 float* __restrict__ C, int M, int N, int K)
{
  __shared__ unsigned short sA[128 * 64];
  __shared__ unsigned short sB[128 * 64];
  const int tid  = threadIdx.x;
  const int lane = tid & 63;
  const int wid  = tid >> 6;
  const int wm = wid >> 1, wn = wid & 1;
  const int ntn = N / 128;
  const int tm = blockIdx.x / ntn, tn = blockIdx.x - tm * ntn;
  const int row0 = tm * 128, col0 = tn * 128;

  f32x4 acc[4][4];
#pragma unroll
  for (int m = 0; m < 4; ++m)
#pragma unroll
    for (int n = 0; n < 4; ++n)
#pragma unroll
      for (int j = 0; j < 4; ++j) acc[m][n][j] = 0.0f;

  const int lrow = lane & 15;
  const int lko  = (lane >> 4) * 8;

  for (int k0 = 0; k0 < K; k0 += 64) {
    if (XB16) {
#pragma unroll
      for (int i = 0; i < 4; ++i) {
        const int wbase = i * 256 + (wid << 6);
        const int c = wbase + lane;
        const int r = c >> 3, ce = (c & 7) * 8;
        gload_lds16(sA + (size_t)wbase * 8, Abf + (size_t)(row0 + r) * K + k0 + ce);
      }
    } else {
#pragma unroll
      for (int i = 0; i < 4; ++i) {
        const int c = i * 256 + tid;
        const int r = c >> 3, ce = (c & 7) * 8;
        const float4* p = (const float4*)(Af32 + (size_t)(row0 + r) * K + k0 + ce);
        float4 aa = p[0], bb = p[1];
        u16x8 v;
        v[0] = f2bf(aa.x); v[1] = f2bf(aa.y); v[2] = f2bf(aa.z); v[3] = f2bf(aa.w);
        v[4] = f2bf(bb.x); v[5] = f2bf(bb.y); v[6] = f2bf(bb.z); v[7] = f2bf(bb.w);
        *(u16x8*)(sA + c * 8) = v;
      }
    }
#pragma unroll
    for (int i = 0; i < 4; ++i) {
      const int wbase = i * 256 + (wid << 6);
      const int c = wbase + lane;
      const int r = c >> 3, ce = (c & 7) * 8;
      gload_lds16(sB + (size_t)wbase * 8, Bbf + (size_t)(col0 + r) * K + k0 + ce);
    }
    __syncthreads();
    bf16x8 af[4][2], bfr[4][2];
#pragma unroll
    for (int m = 0; m < 4; ++m) {
      const int r = wm * 64 + m * 16 + lrow;
#pragma unroll
      for (int kk = 0; kk < 2; ++kk)
        af[m][kk] = *(const bf16x8*)(sA + r * 64 + kk * 32 + lko);
    }
#pragma unroll
    for (int n = 0; n < 4; ++n) {
      const int r = wn * 64 + n * 16 + lrow;
#pragma unroll
      for (int kk = 0; kk < 2; ++kk)
        bfr[n][kk] = *(const bf16x8*)(sB + r * 64 + kk * 32 + lko);
    }
#pragma unroll
    for (int kk = 0; kk < 2; ++kk)
#pragma unroll
      for (int m = 0; m < 4; ++m)
#pragma unroll
        for (int n = 0; n < 4; ++n)
          acc[m][n] = __builtin_amdgcn_mfma_f32_16x16x32_bf16(
              af[m][kk], bfr[n][kk], acc[m][n], 0, 0, 0);
    __syncthreads();
  }
#pragma unroll
  for (int n = 0; n < 4; ++n) {
    const int col = col0 + wn * 64 + n * 16 + lrow;
    const float bv = bias[col];
#pragma unroll
    for (int m = 0; m < 4; ++m) {
      const int row = row0 + wm * 64 + m * 16 + (lane >> 4) * 4;
      const f32x4 v = acc[m][n];
#pragma unroll
      for (int j = 0; j < 4; ++j)
        C[(size_t)(row + j) * N + col] = v[j] + bv;
    }
  }
}

// ---------------- host launch ----------------

extern "C" void kernel_launch(void* const* d_in, const int* in_sizes, int n_in,
                              void* d_out, int out_size, void* d_ws, size_t ws_size,
                              hipStream_t stream) {
  const float* x      = (const float*)d_in[0];
  const int* pw       = (const int*)d_in[1];     // uint8 widened to int32
  const float* scale  = (const float*)d_in[2];
  const float* zp     = (const float*)d_in[3];
  const float* bias   = (const float*)d_in[4];
  float* out = (float*)d_out;

  const int K = IN_F, N = OUT_F;
  const int M = in_sizes[0] / K;                 // 8192

  const size_t xqb = (size_t)M * K;              // 32 MiB i8 X
  const size_t wqb = (size_t)N * K;              // 16 MiB i8 W
  const size_t need_i8 = xqb + wqb + (size_t)M * 4 + (size_t)M * 4;

  const size_t xbytes = (size_t)M * K * 2;       // 64 MiB bf16 X
  const size_t wbytes = (size_t)N * K * 2;       // 32 MiB bf16 W

  if (ws_size >= need_i8 && (M & 255) == 0) {
    signed char* Xq = (signed char*)d_ws;
    signed char* Wq = (signed char*)d_ws + xqb;
    float* sx  = (float*)((char*)d_ws + xqb + wqb);
    int* rsum  = (int*)((char*)d_ws + xqb + wqb + (size_t)M * 4);
    quant_x_kernel<<<M, 256, 0, stream>>>(x, Xq, sx, rsum);
    unpack_w_kernel<<<(OUT_F / 2) * (IN_F / 8) / 256, 256, 0, stream>>>(pw, Wq);
    gemm256_i8_kernel<<<(M / 256) * (N / 256), 512, 0, stream>>>(
        Xq, Wq, sx, rsum, scale, zp, bias, out, M, N, K);
  } else if (ws_size >= xbytes + wbytes) {
    unsigned short* Xb = (unsigned short*)d_ws;
    unsigned short* Wb = (unsigned short*)((char*)d_ws + xbytes);
    cvt_x_kernel<<<2048, 256, 0, stream>>>(x, Xb, (long)M * K / 8);
    dequant_w_kernel<<<(OUT_F / 2) * (IN_F / 8) / 256, 256, 0, stream>>>(pw, scale, zp, Wb);
    gemm_kernel<true><<<(M / 128) * (N / 128), 256, 0, stream>>>(
        Xb, nullptr, Wb, bias, out, M, N, K);
  } else {
    unsigned short* Wb = (unsigned short*)d_ws;  // requires >= 32 MiB ws
    dequant_w_kernel<<<(OUT_F / 2) * (IN_F / 8) / 256, 256, 0, stream>>>(pw, scale, zp, Wb);
    gemm_kernel<false><<<(M / 128) * (N / 128), 256, 0, stream>>>(
        nullptr, x, Wb, bias, out, M, N, K);
  }
}